// Round 13
// baseline (112.734 us; speedup 1.0000x reference)
//
#include <hip/hip_runtime.h>
#include <math.h>

#define B_ 8
#define NL 64
#define NR 512
#define FD 128
#define HID 128
#define KM 10
#define P_ 262144
#define NSAMP 32768
#define M_ 131072
#define LDH 136   // padded LDS row stride in bf16 elems (272B, breaks bank conflicts)

typedef short bf16x8 __attribute__((ext_vector_type(8)));
typedef float f32x4 __attribute__((ext_vector_type(4)));

static __device__ __forceinline__ ushort f2bf(float x) {
    union { float f; unsigned int u; } v; v.f = x;
    unsigned int r = v.u + 0x7FFFu + ((v.u >> 16) & 1u);
    return (ushort)(r >> 16);
}
static __device__ __forceinline__ float elu1(float x) {
    return x > 0.f ? x : (__expf(x) - 1.f);
}

// ---------------- k1: U/V GEMM + col partials; blocks >=576 do weight pre-swizzle ----------------
__global__ __launch_bounds__(128) void k1_uv(const float* __restrict__ flig,
        const float* __restrict__ frec, const float* __restrict__ W1, const float* __restrict__ b1,
        const float* __restrict__ Wc1, const float* __restrict__ Wpi,
        const float* __restrict__ Wsig, const float* __restrict__ Wmu,
        float* __restrict__ U, float* __restrict__ V,
        float* __restrict__ partS, float* __restrict__ partS2,
        ushort* __restrict__ wB, ushort* __restrict__ wBg) {
    __shared__ float fr[8][128];
    int bid = blockIdx.x, c = threadIdx.x;
    if (bid >= 576) {   // weight pre-swizzle path (128 blocks x 128 threads = 16384)
        int idx = (bid - 576) * 128 + c;
        {
            int j = idx & 7, lane = (idx >> 3) & 63, ks = (idx >> 9) & 3, ni = idx >> 11;
            int lrow = lane & 15, kgrp = lane >> 4;
            int n = ni * 16 + lrow, k = ks * 32 + kgrp * 8 + j;
            wB[idx] = f2bf(Wc1[k * HID + n]);
        }
        if (idx < 4096) {
            int j = idx & 7, lane = (idx >> 3) & 63, ks = (idx >> 9) & 3, ni = (idx >> 11) & 1;
            int lrow = lane & 15, kgrp = lane >> 4;
            int n = ni * 16 + lrow, k = ks * 32 + kgrp * 8 + j;
            float wv = 0.f;
            if (n < 10) wv = Wpi[k * KM + n];
            else if (n < 20) wv = Wsig[k * KM + (n - 10)];
            else if (n < 30) wv = Wmu[k * KM + (n - 20)];
            wBg[idx] = f2bf(wv);
        }
        return;
    }
    const float* feat; const float* Wb; float* outp; float bias;
    if (bid < 64) {
        int rowbase = bid * 8;
        feat = flig + rowbase * FD; Wb = W1; outp = U + rowbase * HID; bias = b1[c];
    } else {
        int rowbase = (bid - 64) * 8;
        feat = frec + rowbase * FD; Wb = W1 + FD * HID; outp = V + rowbase * HID; bias = 0.f;
    }
    #pragma unroll
    for (int rr = 0; rr < 8; rr++) fr[rr][c] = feat[rr * FD + c];
    __syncthreads();
    float acc[8];
    #pragma unroll
    for (int rr = 0; rr < 8; rr++) acc[rr] = bias;
    #pragma unroll 4
    for (int k = 0; k < FD; k++) {
        float wv = Wb[k * HID + c];
        #pragma unroll
        for (int rr = 0; rr < 8; rr++) acc[rr] += fr[rr][k] * wv;
    }
    float su = 0.f, su2 = 0.f;
    #pragma unroll
    for (int rr = 0; rr < 8; rr++) {
        outp[rr * HID + c] = acc[rr];
        su += acc[rr]; su2 += acc[rr] * acc[rr];
    }
    partS[bid * 128 + c] = su;
    partS2[bid * 128 + c] = su2;
}

// ---------------- k2: fused BN1 stats reduce + finalize (grid 1 x 1024) ----------------
__global__ __launch_bounds__(1024) void k2_bn1(const float* __restrict__ partS, const float* __restrict__ partS2,
        const float* __restrict__ g1, const float* __restrict__ beta1,
        float* __restrict__ scale1, float* __restrict__ shift1) {
    __shared__ float sU[8][128], sU2[8][128], sV[8][128], sV2[8][128];
    int t = threadIdx.x, c = t & 127, b = t >> 7;
    float su = 0.f, su2 = 0.f;
    #pragma unroll
    for (int j = 0; j < 8; j++) { int row = b * 8 + j; su += partS[row * 128 + c]; su2 += partS2[row * 128 + c]; }
    float sv = 0.f, sv2 = 0.f;
    for (int j = 0; j < 64; j++) { int row = 64 + b * 64 + j; sv += partS[row * 128 + c]; sv2 += partS2[row * 128 + c]; }
    sU[b][c] = su; sU2[b][c] = su2; sV[b][c] = sv; sV2[b][c] = sv2;
    __syncthreads();
    if (t < 128) {
        float sum = 0.f, ssq = 0.f;
        #pragma unroll
        for (int bb = 0; bb < 8; bb++) {
            float s_ = sU[bb][t], v_ = sV[bb][t];
            sum += (float)NR * s_ + (float)NL * v_;
            ssq += (float)NR * sU2[bb][t] + 2.f * s_ * v_ + (float)NL * sV2[bb][t];
        }
        float inv = 1.f / (float)P_;
        float mean = sum * inv;
        float var = ssq * inv - mean * mean;
        float sc = g1[t] * rsqrtf(var + 1e-5f);
        scale1[t] = sc; shift1[t] = beta1[t] - mean * sc;
    }
}

// ---------------- k_sg: blocks 0..1023 = MDN (128 rows each); 1024..1055 = sampled BN2 stats ----------------
__global__ __launch_bounds__(256) void k_sg(const int* __restrict__ mask,
        const float* __restrict__ U, const float* __restrict__ V,
        const float* __restrict__ scale1, const float* __restrict__ shift1,
        const ushort* __restrict__ wB, const ushort* __restrict__ wBg, const float* __restrict__ bc1,
        const float* __restrict__ bpi, const float* __restrict__ bsig, const float* __restrict__ bmu,
        const float* __restrict__ posl, const float* __restrict__ posr,
        float* __restrict__ out_logpi, float* __restrict__ out_sigma, float* __restrict__ out_mu,
        float* __restrict__ mdn_psum, float* __restrict__ mdn_pcnt,
        float* __restrict__ bn2s, float* __restrict__ bn2s2) {
    __shared__ ushort hT[128 * LDH];            // 34816 B -> 4 blocks/CU
    __shared__ int midx[128];
    __shared__ float mdnv[128];
    __shared__ int mdnb[128];
    __shared__ float psLds[8][8], pcLds[8][8];
    int t = threadIdx.x;
    int w = t >> 6, lane = t & 63, lrow = lane & 15, kgrp = lane >> 4;
    int c8 = (t & 15) * 8, rg = t >> 4;
    float4 sc0 = *(const float4*)&scale1[c8], sc1 = *(const float4*)&scale1[c8 + 4];
    float4 sh0 = *(const float4*)&shift1[c8], sh1 = *(const float4*)&shift1[c8 + 4];

    if (blockIdx.x < 1024) {
        // ================= MDN path (128 rows) =================
        float* stageF = (float*)hT;
        float* zl   = stageF;                    // 128*33 = 4224 floats
        float* bufA = stageF + 4352;             // 1280 floats
        float* bufB = stageF + 5632;
        float* bufC = stageF + 6912;             // ends 8192 floats = 32768 B
        int bid = blockIdx.x;
        int m0 = bid * 128;
        if (t < 128) midx[t] = mask[m0 + t];
        __syncthreads();
        #pragma unroll
        for (int rr = rg; rr < 128; rr += 16) {
            int i = midx[rr];
            int bl = i >> 9, b = i >> 15, r = i & 511;
            const float* up = &U[bl * HID + c8];
            const float* vp = &V[(b * NR + r) * HID + c8];
            float4 u0 = *(const float4*)up, u1 = *(const float4*)(up + 4);
            float4 v0 = *(const float4*)vp, v1 = *(const float4*)(vp + 4);
            union { bf16x8 v; ushort u[8]; } o;
            o.u[0] = f2bf(elu1(fmaf(u0.x + v0.x, sc0.x, sh0.x)));
            o.u[1] = f2bf(elu1(fmaf(u0.y + v0.y, sc0.y, sh0.y)));
            o.u[2] = f2bf(elu1(fmaf(u0.z + v0.z, sc0.z, sh0.z)));
            o.u[3] = f2bf(elu1(fmaf(u0.w + v0.w, sc0.w, sh0.w)));
            o.u[4] = f2bf(elu1(fmaf(u1.x + v1.x, sc1.x, sh1.x)));
            o.u[5] = f2bf(elu1(fmaf(u1.y + v1.y, sc1.y, sh1.y)));
            o.u[6] = f2bf(elu1(fmaf(u1.z + v1.z, sc1.z, sh1.z)));
            o.u[7] = f2bf(elu1(fmaf(u1.w + v1.w, sc1.w, sh1.w)));
            *(bf16x8*)&hT[rr * LDH + c8] = o.v;
        }
        __syncthreads();
        int wrow = w * 32;
        f32x4 acc[2][2];
        #pragma unroll
        for (int mi = 0; mi < 2; mi++)
            #pragma unroll
            for (int ni = 0; ni < 2; ni++) acc[mi][ni] = (f32x4){0.f, 0.f, 0.f, 0.f};
        const bf16x8* wBv = (const bf16x8*)wBg;
        #pragma unroll
        for (int ks = 0; ks < 4; ks++) {
            int ko = ks * 32 + kgrp * 8;
            bf16x8 a0 = *(const bf16x8*)&hT[(wrow + lrow) * LDH + ko];
            bf16x8 a1 = *(const bf16x8*)&hT[(wrow + 16 + lrow) * LDH + ko];
            bf16x8 b0 = wBv[ks * 64 + lane];
            bf16x8 b1 = wBv[(4 + ks) * 64 + lane];
            acc[0][0] = __builtin_amdgcn_mfma_f32_16x16x32_bf16(a0, b0, acc[0][0], 0, 0, 0);
            acc[0][1] = __builtin_amdgcn_mfma_f32_16x16x32_bf16(a0, b1, acc[0][1], 0, 0, 0);
            acc[1][0] = __builtin_amdgcn_mfma_f32_16x16x32_bf16(a1, b0, acc[1][0], 0, 0, 0);
            acc[1][1] = __builtin_amdgcn_mfma_f32_16x16x32_bf16(a1, b1, acc[1][1], 0, 0, 0);
        }
        __syncthreads();   // all hT reads done before zl alias writes
        #pragma unroll
        for (int mi = 0; mi < 2; mi++)
            #pragma unroll
            for (int ni = 0; ni < 2; ni++)
                #pragma unroll
                for (int reg = 0; reg < 4; reg++) {
                    int row = wrow + mi * 16 + kgrp * 4 + reg;
                    zl[row * 33 + ni * 16 + lrow] = acc[mi][ni][reg];
                }
        __syncthreads();
        if (t < 128) {
            float zv[30];
            #pragma unroll
            for (int j = 0; j < 30; j++) zv[j] = zl[t * 33 + j];
            float lp[10], mx = -1e30f;
            #pragma unroll
            for (int j = 0; j < 10; j++) { lp[j] = zv[j] + bpi[j]; mx = fmaxf(mx, lp[j]); }
            float se = 0.f;
            #pragma unroll
            for (int j = 0; j < 10; j++) se += __expf(lp[j] - mx);
            float lse = mx + __logf(se);
            #pragma unroll
            for (int j = 0; j < 10; j++) lp[j] -= lse;
            float sg[10], muv[10];
            #pragma unroll
            for (int j = 0; j < 10; j++) sg[j] = elu1(zv[10 + j] + bsig[j]) + 1.1f;
            #pragma unroll
            for (int j = 0; j < 10; j++) muv[j] = elu1(zv[20 + j] + bmu[j]) + 1.0f;
            int i = midx[t];
            int bl = i >> 9, b = i >> 15, r = i & 511;
            float dx = posl[bl * 3]     - posr[(b * NR + r) * 3];
            float dy = posl[bl * 3 + 1] - posr[(b * NR + r) * 3 + 1];
            float dz = posl[bl * 3 + 2] - posr[(b * NR + r) * 3 + 2];
            float y = sqrtf(dx * dx + dy * dy + dz * dz);
            float tt[10], mm = -1e30f;
            #pragma unroll
            for (int j = 0; j < 10; j++) {
                float q = (y - muv[j]) / sg[j];
                float llv = -0.5f * q * q - __logf(sg[j]) - 0.91893853320467274f;
                tt[j] = lp[j] + llv; mm = fmaxf(mm, tt[j]);
            }
            float s2e = 0.f;
            #pragma unroll
            for (int j = 0; j < 10; j++) s2e += __expf(tt[j] - mm);
            float mdn = -(mm + __logf(s2e));
            #pragma unroll
            for (int j = 0; j < 10; j++) { bufA[t * 10 + j] = lp[j]; bufB[t * 10 + j] = sg[j]; bufC[t * 10 + j] = muv[j]; }
            mdnv[t] = mdn; mdnb[t] = b;
        }
        __syncthreads();
        {
            float4* oA = (float4*)&out_logpi[m0 * 10];
            float4* oB = (float4*)&out_sigma[m0 * 10];
            float4* oC = (float4*)&out_mu[m0 * 10];
            const float4* bA = (const float4*)bufA;
            const float4* bB = (const float4*)bufB;
            const float4* bC = (const float4*)bufC;
            #pragma unroll
            for (int i4 = t; i4 < 320; i4 += 256) { oA[i4] = bA[i4]; oB[i4] = bB[i4]; oC[i4] = bC[i4]; }
        }
        if (t < 64) {   // deterministic fixed-order partial sums: 8 chunks x 8 batches
            int bb = t & 7, chunk = t >> 3;
            float s = 0.f; int cnt = 0;
            for (int rr = chunk * 16; rr < chunk * 16 + 16; rr++)
                if (mdnb[rr] == bb) { s += mdnv[rr]; cnt++; }
            psLds[chunk][bb] = s; pcLds[chunk][bb] = (float)cnt;
        }
        __syncthreads();
        if (t < 8) {
            float s = 0.f, cnt = 0.f;
            #pragma unroll
            for (int chunk = 0; chunk < 8; chunk++) { s += psLds[chunk][t]; cnt += pcLds[chunk][t]; }
            mdn_psum[bid * 8 + t] = s; mdn_pcnt[bid * 8 + t] = cnt;
        }
    } else {
        // ================= sampled BN2 stats path: 32 blocks x 8 tile-pairs =================
        int sid = blockIdx.x - 1024;
        const bf16x8* wBv = (const bf16x8*)wB;
        bf16x8 Bfr[2][4];
        #pragma unroll
        for (int nil = 0; nil < 2; nil++)
            #pragma unroll
            for (int ks = 0; ks < 4; ks++)
                Bfr[nil][ks] = wBv[((w * 2 + nil) * 4 + ks) * 64 + lane];
        float bc1v[2] = { bc1[w * 32 + lrow], bc1[w * 32 + 16 + lrow] };
        float s[2] = {0.f, 0.f}, s2[2] = {0.f, 0.f};
        for (int p = 0; p < 8; p++) {
            int bl0 = sid * 16 + p * 2, bl1 = bl0 + 1;
            float4 uA0 = *(const float4*)&U[bl0 * HID + c8], uA1 = *(const float4*)&U[bl0 * HID + c8 + 4];
            float4 uB0 = *(const float4*)&U[bl1 * HID + c8], uB1 = *(const float4*)&U[bl1 * HID + c8 + 4];
            float4 ubA0, ubA1, ubB0, ubB1;
            ubA0.x = fmaf(uA0.x, sc0.x, sh0.x); ubA0.y = fmaf(uA0.y, sc0.y, sh0.y);
            ubA0.z = fmaf(uA0.z, sc0.z, sh0.z); ubA0.w = fmaf(uA0.w, sc0.w, sh0.w);
            ubA1.x = fmaf(uA1.x, sc1.x, sh1.x); ubA1.y = fmaf(uA1.y, sc1.y, sh1.y);
            ubA1.z = fmaf(uA1.z, sc1.z, sh1.z); ubA1.w = fmaf(uA1.w, sc1.w, sh1.w);
            ubB0.x = fmaf(uB0.x, sc0.x, sh0.x); ubB0.y = fmaf(uB0.y, sc0.y, sh0.y);
            ubB0.z = fmaf(uB0.z, sc0.z, sh0.z); ubB0.w = fmaf(uB0.w, sc0.w, sh0.w);
            ubB1.x = fmaf(uB1.x, sc1.x, sh1.x); ubB1.y = fmaf(uB1.y, sc1.y, sh1.y);
            ubB1.z = fmaf(uB1.z, sc1.z, sh1.z); ubB1.w = fmaf(uB1.w, sc1.w, sh1.w);
            int vbatch = (bl0 >> 6) << 9;
            __syncthreads();   // hT reuse guard
            #pragma unroll
            for (int k = 0; k < 8; k++) {
                int rr = rg + k * 16;
                int j = rr & 63;
                const float* vp = &V[(vbatch + j * 8) * HID + c8];
                float4 v0 = *(const float4*)vp, v1 = *(const float4*)(vp + 4);
                float4 ub0 = (k < 4) ? ubA0 : ubB0;
                float4 ub1 = (k < 4) ? ubA1 : ubB1;
                union { bf16x8 v; ushort u[8]; } o;
                o.u[0] = f2bf(elu1(fmaf(v0.x, sc0.x, ub0.x)));
                o.u[1] = f2bf(elu1(fmaf(v0.y, sc0.y, ub0.y)));
                o.u[2] = f2bf(elu1(fmaf(v0.z, sc0.z, ub0.z)));
                o.u[3] = f2bf(elu1(fmaf(v0.w, sc0.w, ub0.w)));
                o.u[4] = f2bf(elu1(fmaf(v1.x, sc1.x, ub1.x)));
                o.u[5] = f2bf(elu1(fmaf(v1.y, sc1.y, ub1.y)));
                o.u[6] = f2bf(elu1(fmaf(v1.z, sc1.z, ub1.z)));
                o.u[7] = f2bf(elu1(fmaf(v1.w, sc1.w, ub1.w)));
                *(bf16x8*)&hT[rr * LDH + c8] = o.v;
            }
            __syncthreads();
            f32x4 acc[8][2];
            #pragma unroll
            for (int m = 0; m < 8; m++) { acc[m][0] = (f32x4){0,0,0,0}; acc[m][1] = (f32x4){0,0,0,0}; }
            __builtin_amdgcn_s_setprio(1);
            #pragma unroll
            for (int m = 0; m < 8; m++) {
                #pragma unroll
                for (int ks = 0; ks < 4; ks++) {
                    bf16x8 a = *(const bf16x8*)&hT[(m * 16 + lrow) * LDH + ks * 32 + kgrp * 8];
                    acc[m][0] = __builtin_amdgcn_mfma_f32_16x16x32_bf16(a, Bfr[0][ks], acc[m][0], 0, 0, 0);
                    acc[m][1] = __builtin_amdgcn_mfma_f32_16x16x32_bf16(a, Bfr[1][ks], acc[m][1], 0, 0, 0);
                }
            }
            __builtin_amdgcn_s_setprio(0);
            #pragma unroll
            for (int nil = 0; nil < 2; nil++)
                #pragma unroll
                for (int reg = 0; reg < 4; reg++)
                    #pragma unroll
                    for (int m = 0; m < 8; m++) {
                        float vv = acc[m][nil][reg] + bc1v[nil];
                        s[nil] += vv; s2[nil] += vv * vv;
                    }
        }
        #pragma unroll
        for (int nil = 0; nil < 2; nil++) {
            s[nil] += __shfl_xor(s[nil], 16);  s[nil] += __shfl_xor(s[nil], 32);
            s2[nil] += __shfl_xor(s2[nil], 16); s2[nil] += __shfl_xor(s2[nil], 32);
        }
        if (lane < 16) {
            bn2s[sid * 128 + w * 32 + lane]       = s[0];
            bn2s[sid * 128 + w * 32 + 16 + lane]  = s[1];
            bn2s2[sid * 128 + w * 32 + lane]      = s2[0];
            bn2s2[sid * 128 + w * 32 + 16 + lane] = s2[1];
        }
    }
}

// ---------------- k3f: per-block BN2 finalize + fused GEMM + contact epilogue (grid 2048) ----------------
__global__ __launch_bounds__(256, 2) void k3f_gemm(const float* __restrict__ U, const float* __restrict__ V,
        const ushort* __restrict__ wB,
        const float* __restrict__ scale1, const float* __restrict__ shift1,
        const float* __restrict__ bn2s, const float* __restrict__ bn2s2,
        const float* __restrict__ gc, const float* __restrict__ betac, const float* __restrict__ bc1,
        const float* __restrict__ Wc2, const float* __restrict__ bc2,
        const float* __restrict__ psum, const float* __restrict__ pcnt,
        const float* __restrict__ posl, const float* __restrict__ posr,
        float* __restrict__ outc, float* __restrict__ outt, float* __restrict__ prob) {
    __shared__ ushort hT[128 * LDH];     // 34816 B
    __shared__ float part[4][128];       // 2048 B (also prologue scratch)
    __shared__ float afL[128], bfL[128]; // 1024 B -> total ~37.9 KB => 4 blocks/CU
    int bid = blockIdx.x, t = threadIdx.x;
    int bl = bid >> 2, it = bid & 3;
    int w = t >> 6, lane = t & 63, lrow = lane & 15, kgrp = lane >> 4;
    // ---- prologue: per-block redundant BN2 finalize from 32-row partials ----
    {
        int c = t & 127, half = t >> 7;
        float s = 0.f, s2 = 0.f;
        #pragma unroll
        for (int r = half * 16; r < half * 16 + 16; r++) { s += bn2s[r * 128 + c]; s2 += bn2s2[r * 128 + c]; }
        part[half][c] = s; part[2 + half][c] = s2;
        __syncthreads();
        if (t < 128) {
            float ss = part[0][t] + part[1][t], ss2 = part[2][t] + part[3][t];
            float inv = 1.f / (float)NSAMP;
            float mean = ss * inv, var = ss2 * inv - mean * mean;
            float sc = gc[t] * rsqrtf(var + 1e-5f);
            afL[t] = sc;
            bfL[t] = (bc1[t] - mean) * sc + betac[t];
        }
        __syncthreads();
    }
    // ---- block 0: prob segment-mean (psum complete before this kernel) ----
    if (bid == 0) {
        float* pscr = (float*)hT;   // 512 floats, pre-staging
        int bb = t & 7, g = t >> 3;
        float s = 0.f, cnum = 0.f;
        for (int r = g; r < 1024; r += 32) { s += psum[r * 8 + bb]; cnum += pcnt[r * 8 + bb]; }
        pscr[t] = s; pscr[256 + t] = cnum;
        __syncthreads();
        if (t < 8) {
            float ss = 0.f, cc = 0.f;
            #pragma unroll
            for (int g2 = 0; g2 < 32; g2++) { ss += pscr[g2 * 8 + t]; cc += pscr[256 + g2 * 8 + t]; }
            prob[t] = ss / fmaxf(cc, 1.f);
        }
        __syncthreads();   // before staging overwrites hT
    }
    const bf16x8* wBv = (const bf16x8*)wB;
    bf16x8 Bfr[2][4];
    #pragma unroll
    for (int nil = 0; nil < 2; nil++)
        #pragma unroll
        for (int ks = 0; ks < 4; ks++)
            Bfr[nil][ks] = wBv[((w * 2 + nil) * 4 + ks) * 64 + lane];
    float av[2], bv[2], wv[2];
    #pragma unroll
    for (int nil = 0; nil < 2; nil++) {
        int c = w * 32 + nil * 16 + lrow;
        av[nil] = afL[c]; bv[nil] = bfL[c]; wv[nil] = Wc2[c];
    }
    float bc2v = bc2[0];
    int c8 = (t & 15) * 8, rg = t >> 4;
    float4 sc0 = *(const float4*)&scale1[c8], sc1 = *(const float4*)&scale1[c8 + 4];
    float4 sh0 = *(const float4*)&shift1[c8], sh1 = *(const float4*)&shift1[c8 + 4];
    float4 u0 = *(const float4*)&U[bl * HID + c8];
    float4 u1 = *(const float4*)&U[bl * HID + c8 + 4];
    float4 ub0, ub1;
    ub0.x = fmaf(u0.x, sc0.x, sh0.x); ub0.y = fmaf(u0.y, sc0.y, sh0.y);
    ub0.z = fmaf(u0.z, sc0.z, sh0.z); ub0.w = fmaf(u0.w, sc0.w, sh0.w);
    ub1.x = fmaf(u1.x, sc1.x, sh1.x); ub1.y = fmaf(u1.y, sc1.y, sh1.y);
    ub1.z = fmaf(u1.z, sc1.z, sh1.z); ub1.w = fmaf(u1.w, sc1.w, sh1.w);
    int vtile = ((bl >> 6) << 9) + it * 128;
    // stage h tile
    #pragma unroll
    for (int rr = rg; rr < 128; rr += 16) {
        const float* vp = &V[(vtile + rr) * HID + c8];
        float4 v0 = *(const float4*)vp, v1 = *(const float4*)(vp + 4);
        union { bf16x8 v; ushort u[8]; } o;
        o.u[0] = f2bf(elu1(fmaf(v0.x, sc0.x, ub0.x)));
        o.u[1] = f2bf(elu1(fmaf(v0.y, sc0.y, ub0.y)));
        o.u[2] = f2bf(elu1(fmaf(v0.z, sc0.z, ub0.z)));
        o.u[3] = f2bf(elu1(fmaf(v0.w, sc0.w, ub0.w)));
        o.u[4] = f2bf(elu1(fmaf(v1.x, sc1.x, ub1.x)));
        o.u[5] = f2bf(elu1(fmaf(v1.y, sc1.y, ub1.y)));
        o.u[6] = f2bf(elu1(fmaf(v1.z, sc1.z, ub1.z)));
        o.u[7] = f2bf(elu1(fmaf(v1.w, sc1.w, ub1.w)));
        *(bf16x8*)&hT[rr * LDH + c8] = o.v;
    }
    __syncthreads();
    f32x4 acc[8][2];
    #pragma unroll
    for (int m = 0; m < 8; m++) { acc[m][0] = (f32x4){0,0,0,0}; acc[m][1] = (f32x4){0,0,0,0}; }
    __builtin_amdgcn_s_setprio(1);
    #pragma unroll
    for (int m = 0; m < 8; m++) {
        #pragma unroll
        for (int ks = 0; ks < 4; ks++) {
            bf16x8 a = *(const bf16x8*)&hT[(m * 16 + lrow) * LDH + ks * 32 + kgrp * 8];
            acc[m][0] = __builtin_amdgcn_mfma_f32_16x16x32_bf16(a, Bfr[0][ks], acc[m][0], 0, 0, 0);
            acc[m][1] = __builtin_amdgcn_mfma_f32_16x16x32_bf16(a, Bfr[1][ks], acc[m][1], 0, 0, 0);
        }
    }
    __builtin_amdgcn_s_setprio(0);
    // fused epilogue: relu(acc*Af + Bf2)·Wc2, per-wave partial, 16-lane shfl reduce
    #pragma unroll
    for (int reg = 0; reg < 4; reg++) {
        float pr[8];
        #pragma unroll
        for (int m = 0; m < 8; m++) pr[m] = 0.f;
        #pragma unroll
        for (int nil = 0; nil < 2; nil++)
            #pragma unroll
            for (int m = 0; m < 8; m++) {
                float x = fmaf(acc[m][nil][reg], av[nil], bv[nil]);
                pr[m] += fmaxf(x, 0.f) * wv[nil];
            }
        #pragma unroll
        for (int m = 0; m < 8; m++) {
            pr[m] += __shfl_xor(pr[m], 1); pr[m] += __shfl_xor(pr[m], 2);
            pr[m] += __shfl_xor(pr[m], 4); pr[m] += __shfl_xor(pr[m], 8);
        }
        if (lrow == 0) {
            #pragma unroll
            for (int m = 0; m < 8; m++) part[w][m * 16 + kgrp * 4 + reg] = pr[m];
        }
    }
    __syncthreads();
    if (t < 128) {
        int row = bid * 128 + t;
        outc[row] = part[0][t] + part[1][t] + part[2][t] + part[3][t] + bc2v;
        int pbl = row >> 9, pb = row >> 15, pr_ = row & 511;
        float dx = posl[pbl * 3]     - posr[(pb * NR + pr_) * 3];
        float dy = posl[pbl * 3 + 1] - posr[(pb * NR + pr_) * 3 + 1];
        float dz = posl[pbl * 3 + 2] - posr[(pb * NR + pr_) * 3 + 2];
        float y = sqrtf(dx * dx + dy * dy + dz * dz);
        outt[row] = (y < 8.0f) ? 1.0f : 0.0f;
    }
}

extern "C" void kernel_launch(void* const* d_in, const int* in_sizes, int n_in,
                              void* d_out, int out_size, void* d_ws, size_t ws_size,
                              hipStream_t stream) {
    const float* flig  = (const float*)d_in[0];
    const float* posl  = (const float*)d_in[1];
    const float* frec  = (const float*)d_in[3];
    const float* posr  = (const float*)d_in[4];
    const int*   mask  = (const int*)d_in[6];
    const float* W1    = (const float*)d_in[7];
    const float* b1    = (const float*)d_in[8];
    const float* g1    = (const float*)d_in[9];
    const float* beta1 = (const float*)d_in[10];
    const float* Wpi   = (const float*)d_in[11];
    const float* bpi   = (const float*)d_in[12];
    const float* Wsig  = (const float*)d_in[13];
    const float* bsig  = (const float*)d_in[14];
    const float* Wmu   = (const float*)d_in[15];
    const float* bmu   = (const float*)d_in[16];
    const float* Wc1   = (const float*)d_in[17];
    const float* bc1   = (const float*)d_in[18];
    const float* gc    = (const float*)d_in[19];
    const float* betac = (const float*)d_in[20];
    const float* Wc2   = (const float*)d_in[21];
    const float* bc2   = (const float*)d_in[22];

    float* ws = (float*)d_ws;
    float* U      = ws;                 // 65536
    float* V      = ws + 65536;         // 524288 (end 589824)
    float* scale1 = ws + 589824;        // 128
    float* shift1 = ws + 589952;        // (end 590080)
    ushort* wB    = (ushort*)(ws + 590080);   // 16384 bf16 = 8192 f (end 598272)
    ushort* wBg   = (ushort*)(ws + 598272);   // 4096 bf16 = 2048 f (end 600320)
    float* bn2s   = ws + 600320;        // 32*128 = 4096 (end 604416)
    float* bn2s2  = ws + 604416;        // (end 608512)
    float* psum   = ws + 608512;        // 8192 (end 616704)
    float* pcnt   = ws + 616704;        // (end 624896)
    float* partS  = ws + 624896;        // 576*128 = 73728 (end 698624)
    float* partS2 = ws + 698624;        // (end 772352)

    float* out = (float*)d_out;
    float* out_logpi   = out;
    float* out_sigma   = out + 1310720;
    float* out_mu      = out + 2621440;
    float* out_prob    = out + 3932160;
    float* out_contact = out + 3932168;
    float* out_truth   = out + 4194312;

    k1_uv<<<dim3(704), dim3(128), 0, stream>>>(flig, frec, W1, b1, Wc1, Wpi, Wsig, Wmu,
        U, V, partS, partS2, wB, wBg);
    k2_bn1<<<dim3(1), dim3(1024), 0, stream>>>(partS, partS2, g1, beta1, scale1, shift1);
    k_sg<<<dim3(1056), dim3(256), 0, stream>>>(mask, U, V, scale1, shift1, wB, wBg, bc1,
        bpi, bsig, bmu, posl, posr, out_logpi, out_sigma, out_mu, psum, pcnt, bn2s, bn2s2);
    k3f_gemm<<<dim3(2048), dim3(256), 0, stream>>>(U, V, wB, scale1, shift1, bn2s, bn2s2,
        gc, betac, bc1, Wc2, bc2, psum, pcnt, posl, posr, out_contact, out_truth, out_prob);
}

// Round 14
// 92.794 us; speedup vs baseline: 1.2149x; 1.2149x over previous
//
#include <hip/hip_runtime.h>
#include <math.h>

#define B_ 8
#define NL 64
#define NR 512
#define FD 128
#define HID 128
#define KM 10
#define P_ 262144
#define NSAMP 32768
#define M_ 131072
#define LDH 136   // padded LDS row stride in bf16 elems (272B, breaks bank conflicts)

typedef short bf16x8 __attribute__((ext_vector_type(8)));
typedef float f32x4 __attribute__((ext_vector_type(4)));

static __device__ __forceinline__ ushort f2bf(float x) {
    union { float f; unsigned int u; } v; v.f = x;
    unsigned int r = v.u + 0x7FFFu + ((v.u >> 16) & 1u);
    return (ushort)(r >> 16);
}
static __device__ __forceinline__ float elu1(float x) {
    return x > 0.f ? x : (__expf(x) - 1.f);
}

// ---------------- k1: U/V GEMM + col partials; blocks >=576 do weight pre-swizzle ----------------
__global__ __launch_bounds__(128) void k1_uv(const float* __restrict__ flig,
        const float* __restrict__ frec, const float* __restrict__ W1, const float* __restrict__ b1,
        const float* __restrict__ Wc1, const float* __restrict__ Wpi,
        const float* __restrict__ Wsig, const float* __restrict__ Wmu,
        float* __restrict__ U, float* __restrict__ V,
        float* __restrict__ partS, float* __restrict__ partS2,
        ushort* __restrict__ wB, ushort* __restrict__ wBg) {
    __shared__ float fr[8][128];
    int bid = blockIdx.x, c = threadIdx.x;
    if (bid >= 576) {   // weight pre-swizzle path (128 blocks x 128 threads = 16384)
        int idx = (bid - 576) * 128 + c;
        {
            int j = idx & 7, lane = (idx >> 3) & 63, ks = (idx >> 9) & 3, ni = idx >> 11;
            int lrow = lane & 15, kgrp = lane >> 4;
            int n = ni * 16 + lrow, k = ks * 32 + kgrp * 8 + j;
            wB[idx] = f2bf(Wc1[k * HID + n]);
        }
        if (idx < 4096) {
            int j = idx & 7, lane = (idx >> 3) & 63, ks = (idx >> 9) & 3, ni = (idx >> 11) & 1;
            int lrow = lane & 15, kgrp = lane >> 4;
            int n = ni * 16 + lrow, k = ks * 32 + kgrp * 8 + j;
            float wv = 0.f;
            if (n < 10) wv = Wpi[k * KM + n];
            else if (n < 20) wv = Wsig[k * KM + (n - 10)];
            else if (n < 30) wv = Wmu[k * KM + (n - 20)];
            wBg[idx] = f2bf(wv);
        }
        return;
    }
    const float* feat; const float* Wb; float* outp; float bias;
    if (bid < 64) {
        int rowbase = bid * 8;
        feat = flig + rowbase * FD; Wb = W1; outp = U + rowbase * HID; bias = b1[c];
    } else {
        int rowbase = (bid - 64) * 8;
        feat = frec + rowbase * FD; Wb = W1 + FD * HID; outp = V + rowbase * HID; bias = 0.f;
    }
    #pragma unroll
    for (int rr = 0; rr < 8; rr++) fr[rr][c] = feat[rr * FD + c];
    __syncthreads();
    float acc[8];
    #pragma unroll
    for (int rr = 0; rr < 8; rr++) acc[rr] = bias;
    #pragma unroll 4
    for (int k = 0; k < FD; k++) {
        float wv = Wb[k * HID + c];
        #pragma unroll
        for (int rr = 0; rr < 8; rr++) acc[rr] += fr[rr][k] * wv;
    }
    float su = 0.f, su2 = 0.f;
    #pragma unroll
    for (int rr = 0; rr < 8; rr++) {
        outp[rr * HID + c] = acc[rr];
        su += acc[rr]; su2 += acc[rr] * acc[rr];
    }
    partS[bid * 128 + c] = su;
    partS2[bid * 128 + c] = su2;
}

// ---------------- k2: fused BN1 stats reduce + finalize (grid 1 x 1024) ----------------
__global__ __launch_bounds__(1024) void k2_bn1(const float* __restrict__ partS, const float* __restrict__ partS2,
        const float* __restrict__ g1, const float* __restrict__ beta1,
        float* __restrict__ scale1, float* __restrict__ shift1) {
    __shared__ float sU[8][128], sU2[8][128], sV[8][128], sV2[8][128];
    int t = threadIdx.x, c = t & 127, b = t >> 7;
    float su = 0.f, su2 = 0.f;
    #pragma unroll
    for (int j = 0; j < 8; j++) { int row = b * 8 + j; su += partS[row * 128 + c]; su2 += partS2[row * 128 + c]; }
    float sv = 0.f, sv2 = 0.f;
    for (int j = 0; j < 64; j++) { int row = 64 + b * 64 + j; sv += partS[row * 128 + c]; sv2 += partS2[row * 128 + c]; }
    sU[b][c] = su; sU2[b][c] = su2; sV[b][c] = sv; sV2[b][c] = sv2;
    __syncthreads();
    if (t < 128) {
        float sum = 0.f, ssq = 0.f;
        #pragma unroll
        for (int bb = 0; bb < 8; bb++) {
            float s_ = sU[bb][t], v_ = sV[bb][t];
            sum += (float)NR * s_ + (float)NL * v_;
            ssq += (float)NR * sU2[bb][t] + 2.f * s_ * v_ + (float)NL * sV2[bb][t];
        }
        float inv = 1.f / (float)P_;
        float mean = sum * inv;
        float var = ssq * inv - mean * mean;
        float sc = g1[t] * rsqrtf(var + 1e-5f);
        scale1[t] = sc; shift1[t] = beta1[t] - mean * sc;
    }
}

// ---------------- k_sg: blocks 0..1023 = MDN (128 rows each); 1024..1279 = sampled BN2 stats ----------------
__global__ __launch_bounds__(256) void k_sg(const int* __restrict__ mask,
        const float* __restrict__ U, const float* __restrict__ V,
        const float* __restrict__ scale1, const float* __restrict__ shift1,
        const ushort* __restrict__ wB, const ushort* __restrict__ wBg, const float* __restrict__ bc1,
        const float* __restrict__ bpi, const float* __restrict__ bsig, const float* __restrict__ bmu,
        const float* __restrict__ posl, const float* __restrict__ posr,
        float* __restrict__ out_logpi, float* __restrict__ out_sigma, float* __restrict__ out_mu,
        float* __restrict__ mdn_psum, float* __restrict__ mdn_pcnt,
        float* __restrict__ bn2s, float* __restrict__ bn2s2) {
    __shared__ ushort hT[128 * LDH];            // 34816 B -> 4 blocks/CU
    __shared__ int midx[128];
    __shared__ float mdnv[128];
    __shared__ int mdnb[128];
    __shared__ float psLds[8][8], pcLds[8][8];
    int t = threadIdx.x;
    int w = t >> 6, lane = t & 63, lrow = lane & 15, kgrp = lane >> 4;
    int c8 = (t & 15) * 8, rg = t >> 4;
    float4 sc0 = *(const float4*)&scale1[c8], sc1 = *(const float4*)&scale1[c8 + 4];
    float4 sh0 = *(const float4*)&shift1[c8], sh1 = *(const float4*)&shift1[c8 + 4];

    if (blockIdx.x < 1024) {
        // ================= MDN path (128 rows) =================
        float* stageF = (float*)hT;
        float* zl   = stageF;                    // 128*33 = 4224 floats
        float* bufA = stageF + 4352;             // 1280 floats
        float* bufB = stageF + 5632;
        float* bufC = stageF + 6912;             // ends 8192 floats = 32768 B
        int bid = blockIdx.x;
        int m0 = bid * 128;
        if (t < 128) midx[t] = mask[m0 + t];
        __syncthreads();
        #pragma unroll
        for (int rr = rg; rr < 128; rr += 16) {
            int i = midx[rr];
            int bl = i >> 9, b = i >> 15, r = i & 511;
            const float* up = &U[bl * HID + c8];
            const float* vp = &V[(b * NR + r) * HID + c8];
            float4 u0 = *(const float4*)up, u1 = *(const float4*)(up + 4);
            float4 v0 = *(const float4*)vp, v1 = *(const float4*)(vp + 4);
            union { bf16x8 v; ushort u[8]; } o;
            o.u[0] = f2bf(elu1(fmaf(u0.x + v0.x, sc0.x, sh0.x)));
            o.u[1] = f2bf(elu1(fmaf(u0.y + v0.y, sc0.y, sh0.y)));
            o.u[2] = f2bf(elu1(fmaf(u0.z + v0.z, sc0.z, sh0.z)));
            o.u[3] = f2bf(elu1(fmaf(u0.w + v0.w, sc0.w, sh0.w)));
            o.u[4] = f2bf(elu1(fmaf(u1.x + v1.x, sc1.x, sh1.x)));
            o.u[5] = f2bf(elu1(fmaf(u1.y + v1.y, sc1.y, sh1.y)));
            o.u[6] = f2bf(elu1(fmaf(u1.z + v1.z, sc1.z, sh1.z)));
            o.u[7] = f2bf(elu1(fmaf(u1.w + v1.w, sc1.w, sh1.w)));
            *(bf16x8*)&hT[rr * LDH + c8] = o.v;
        }
        __syncthreads();
        int wrow = w * 32;
        f32x4 acc[2][2];
        #pragma unroll
        for (int mi = 0; mi < 2; mi++)
            #pragma unroll
            for (int ni = 0; ni < 2; ni++) acc[mi][ni] = (f32x4){0.f, 0.f, 0.f, 0.f};
        const bf16x8* wBv = (const bf16x8*)wBg;
        #pragma unroll
        for (int ks = 0; ks < 4; ks++) {
            int ko = ks * 32 + kgrp * 8;
            bf16x8 a0 = *(const bf16x8*)&hT[(wrow + lrow) * LDH + ko];
            bf16x8 a1 = *(const bf16x8*)&hT[(wrow + 16 + lrow) * LDH + ko];
            bf16x8 b0 = wBv[ks * 64 + lane];
            bf16x8 b1 = wBv[(4 + ks) * 64 + lane];
            acc[0][0] = __builtin_amdgcn_mfma_f32_16x16x32_bf16(a0, b0, acc[0][0], 0, 0, 0);
            acc[0][1] = __builtin_amdgcn_mfma_f32_16x16x32_bf16(a0, b1, acc[0][1], 0, 0, 0);
            acc[1][0] = __builtin_amdgcn_mfma_f32_16x16x32_bf16(a1, b0, acc[1][0], 0, 0, 0);
            acc[1][1] = __builtin_amdgcn_mfma_f32_16x16x32_bf16(a1, b1, acc[1][1], 0, 0, 0);
        }
        __syncthreads();   // all hT reads done before zl alias writes
        #pragma unroll
        for (int mi = 0; mi < 2; mi++)
            #pragma unroll
            for (int ni = 0; ni < 2; ni++)
                #pragma unroll
                for (int reg = 0; reg < 4; reg++) {
                    int row = wrow + mi * 16 + kgrp * 4 + reg;
                    zl[row * 33 + ni * 16 + lrow] = acc[mi][ni][reg];
                }
        __syncthreads();
        if (t < 128) {
            float zv[30];
            #pragma unroll
            for (int j = 0; j < 30; j++) zv[j] = zl[t * 33 + j];
            float lp[10], mx = -1e30f;
            #pragma unroll
            for (int j = 0; j < 10; j++) { lp[j] = zv[j] + bpi[j]; mx = fmaxf(mx, lp[j]); }
            float se = 0.f;
            #pragma unroll
            for (int j = 0; j < 10; j++) se += __expf(lp[j] - mx);
            float lse = mx + __logf(se);
            #pragma unroll
            for (int j = 0; j < 10; j++) lp[j] -= lse;
            float sg[10], muv[10];
            #pragma unroll
            for (int j = 0; j < 10; j++) sg[j] = elu1(zv[10 + j] + bsig[j]) + 1.1f;
            #pragma unroll
            for (int j = 0; j < 10; j++) muv[j] = elu1(zv[20 + j] + bmu[j]) + 1.0f;
            int i = midx[t];
            int bl = i >> 9, b = i >> 15, r = i & 511;
            float dx = posl[bl * 3]     - posr[(b * NR + r) * 3];
            float dy = posl[bl * 3 + 1] - posr[(b * NR + r) * 3 + 1];
            float dz = posl[bl * 3 + 2] - posr[(b * NR + r) * 3 + 2];
            float y = sqrtf(dx * dx + dy * dy + dz * dz);
            float tt[10], mm = -1e30f;
            #pragma unroll
            for (int j = 0; j < 10; j++) {
                float q = (y - muv[j]) / sg[j];
                float llv = -0.5f * q * q - __logf(sg[j]) - 0.91893853320467274f;
                tt[j] = lp[j] + llv; mm = fmaxf(mm, tt[j]);
            }
            float s2e = 0.f;
            #pragma unroll
            for (int j = 0; j < 10; j++) s2e += __expf(tt[j] - mm);
            float mdn = -(mm + __logf(s2e));
            #pragma unroll
            for (int j = 0; j < 10; j++) { bufA[t * 10 + j] = lp[j]; bufB[t * 10 + j] = sg[j]; bufC[t * 10 + j] = muv[j]; }
            mdnv[t] = mdn; mdnb[t] = b;
        }
        __syncthreads();
        {
            float4* oA = (float4*)&out_logpi[m0 * 10];
            float4* oB = (float4*)&out_sigma[m0 * 10];
            float4* oC = (float4*)&out_mu[m0 * 10];
            const float4* bA = (const float4*)bufA;
            const float4* bB = (const float4*)bufB;
            const float4* bC = (const float4*)bufC;
            #pragma unroll
            for (int i4 = t; i4 < 320; i4 += 256) { oA[i4] = bA[i4]; oB[i4] = bB[i4]; oC[i4] = bC[i4]; }
        }
        if (t < 64) {   // deterministic fixed-order partial sums: 8 chunks x 8 batches
            int bb = t & 7, chunk = t >> 3;
            float s = 0.f; int cnt = 0;
            for (int rr = chunk * 16; rr < chunk * 16 + 16; rr++)
                if (mdnb[rr] == bb) { s += mdnv[rr]; cnt++; }
            psLds[chunk][bb] = s; pcLds[chunk][bb] = (float)cnt;
        }
        __syncthreads();
        if (t < 8) {
            float s = 0.f, cnt = 0.f;
            #pragma unroll
            for (int chunk = 0; chunk < 8; chunk++) { s += psLds[chunk][t]; cnt += pcLds[chunk][t]; }
            mdn_psum[bid * 8 + t] = s; mdn_pcnt[bid * 8 + t] = cnt;
        }
    } else {
        // ================= sampled BN2 stats path: 256 blocks x 1 tile-pair =================
        int bid = blockIdx.x - 1024;
        int bl0 = bid * 2, bl1 = bl0 + 1;
        const bf16x8* wBv = (const bf16x8*)wB;
        bf16x8 Bfr[2][4];
        #pragma unroll
        for (int nil = 0; nil < 2; nil++)
            #pragma unroll
            for (int ks = 0; ks < 4; ks++)
                Bfr[nil][ks] = wBv[((w * 2 + nil) * 4 + ks) * 64 + lane];
        float bc1v[2] = { bc1[w * 32 + lrow], bc1[w * 32 + 16 + lrow] };
        float4 uA0 = *(const float4*)&U[bl0 * HID + c8], uA1 = *(const float4*)&U[bl0 * HID + c8 + 4];
        float4 uB0 = *(const float4*)&U[bl1 * HID + c8], uB1 = *(const float4*)&U[bl1 * HID + c8 + 4];
        float4 ubA0, ubA1, ubB0, ubB1;
        ubA0.x = fmaf(uA0.x, sc0.x, sh0.x); ubA0.y = fmaf(uA0.y, sc0.y, sh0.y);
        ubA0.z = fmaf(uA0.z, sc0.z, sh0.z); ubA0.w = fmaf(uA0.w, sc0.w, sh0.w);
        ubA1.x = fmaf(uA1.x, sc1.x, sh1.x); ubA1.y = fmaf(uA1.y, sc1.y, sh1.y);
        ubA1.z = fmaf(uA1.z, sc1.z, sh1.z); ubA1.w = fmaf(uA1.w, sc1.w, sh1.w);
        ubB0.x = fmaf(uB0.x, sc0.x, sh0.x); ubB0.y = fmaf(uB0.y, sc0.y, sh0.y);
        ubB0.z = fmaf(uB0.z, sc0.z, sh0.z); ubB0.w = fmaf(uB0.w, sc0.w, sh0.w);
        ubB1.x = fmaf(uB1.x, sc1.x, sh1.x); ubB1.y = fmaf(uB1.y, sc1.y, sh1.y);
        ubB1.z = fmaf(uB1.z, sc1.z, sh1.z); ubB1.w = fmaf(uB1.w, sc1.w, sh1.w);
        int vbatch = (bl0 >> 6) << 9;
        #pragma unroll
        for (int k = 0; k < 8; k++) {
            int rr = rg + k * 16;
            int j = rr & 63;
            const float* vp = &V[(vbatch + j * 8) * HID + c8];
            float4 v0 = *(const float4*)vp, v1 = *(const float4*)(vp + 4);
            float4 ub0 = (k < 4) ? ubA0 : ubB0;
            float4 ub1 = (k < 4) ? ubA1 : ubB1;
            union { bf16x8 v; ushort u[8]; } o;
            o.u[0] = f2bf(elu1(fmaf(v0.x, sc0.x, ub0.x)));
            o.u[1] = f2bf(elu1(fmaf(v0.y, sc0.y, ub0.y)));
            o.u[2] = f2bf(elu1(fmaf(v0.z, sc0.z, ub0.z)));
            o.u[3] = f2bf(elu1(fmaf(v0.w, sc0.w, ub0.w)));
            o.u[4] = f2bf(elu1(fmaf(v1.x, sc1.x, ub1.x)));
            o.u[5] = f2bf(elu1(fmaf(v1.y, sc1.y, ub1.y)));
            o.u[6] = f2bf(elu1(fmaf(v1.z, sc1.z, ub1.z)));
            o.u[7] = f2bf(elu1(fmaf(v1.w, sc1.w, ub1.w)));
            *(bf16x8*)&hT[rr * LDH + c8] = o.v;
        }
        __syncthreads();
        f32x4 acc[8][2];
        #pragma unroll
        for (int m = 0; m < 8; m++) { acc[m][0] = (f32x4){0,0,0,0}; acc[m][1] = (f32x4){0,0,0,0}; }
        #pragma unroll
        for (int m = 0; m < 8; m++) {
            #pragma unroll
            for (int ks = 0; ks < 4; ks++) {
                bf16x8 a = *(const bf16x8*)&hT[(m * 16 + lrow) * LDH + ks * 32 + kgrp * 8];
                acc[m][0] = __builtin_amdgcn_mfma_f32_16x16x32_bf16(a, Bfr[0][ks], acc[m][0], 0, 0, 0);
                acc[m][1] = __builtin_amdgcn_mfma_f32_16x16x32_bf16(a, Bfr[1][ks], acc[m][1], 0, 0, 0);
            }
        }
        float s[2] = {0.f, 0.f}, s2[2] = {0.f, 0.f};
        #pragma unroll
        for (int nil = 0; nil < 2; nil++)
            #pragma unroll
            for (int reg = 0; reg < 4; reg++)
                #pragma unroll
                for (int m = 0; m < 8; m++) {
                    float vv = acc[m][nil][reg] + bc1v[nil];
                    s[nil] += vv; s2[nil] += vv * vv;
                }
        #pragma unroll
        for (int nil = 0; nil < 2; nil++) {
            s[nil] += __shfl_xor(s[nil], 16);  s[nil] += __shfl_xor(s[nil], 32);
            s2[nil] += __shfl_xor(s2[nil], 16); s2[nil] += __shfl_xor(s2[nil], 32);
        }
        if (lane < 16) {
            bn2s[bid * 128 + w * 32 + lane]       = s[0];
            bn2s[bid * 128 + w * 32 + 16 + lane]  = s[1];
            bn2s2[bid * 128 + w * 32 + lane]      = s2[0];
            bn2s2[bid * 128 + w * 32 + 16 + lane] = s2[1];
        }
    }
}

// ---------------- k4: sampled-BN2 finalize + prob segment-mean (grid 1 x 1024) ----------------
__global__ __launch_bounds__(1024) void k4_bn2(const float* __restrict__ bn2s, const float* __restrict__ bn2s2,
        const float* __restrict__ gc, const float* __restrict__ betac, const float* __restrict__ bc1,
        const float* __restrict__ psum, const float* __restrict__ pcnt,
        float* __restrict__ Af, float* __restrict__ Bf2, float* __restrict__ prob) {
    __shared__ float rs[8][128], rs2[8][128];
    __shared__ float prs[8][128], prc[8][128];
    int t = threadIdx.x, c = t & 127, g = t >> 7;
    float s = 0.f, s2 = 0.f;
    for (int j = 0; j < 32; j++) { int row = g * 32 + j; s += bn2s[row * 128 + c]; s2 += bn2s2[row * 128 + c]; }
    rs[g][c] = s; rs2[g][c] = s2;
    // prob partials: batch g, thread c sums rows c, c+128, ..., c+896 (1024 psum rows)
    float ps = 0.f, pc = 0.f;
    #pragma unroll
    for (int k = 0; k < 8; k++) { int row = c + k * 128; ps += psum[row * 8 + g]; pc += pcnt[row * 8 + g]; }
    prs[g][c] = ps; prc[g][c] = pc;
    __syncthreads();
    for (int off = 64; off > 0; off >>= 1) {
        if (c < off) { prs[g][c] += prs[g][c + off]; prc[g][c] += prc[g][c + off]; }
        __syncthreads();
    }
    if (c == 0) prob[g] = prs[g][0] / fmaxf(prc[g][0], 1.f);
    if (t < 128) {
        float ss = 0.f, ss2 = 0.f;
        #pragma unroll
        for (int gg = 0; gg < 8; gg++) { ss += rs[gg][t]; ss2 += rs2[gg][t]; }
        float inv = 1.f / (float)NSAMP;
        float mean = ss * inv, var = ss2 * inv - mean * mean;
        float sc = gc[t] * rsqrtf(var + 1e-5f);
        Af[t] = sc;
        Bf2[t] = (bc1[t] - mean) * sc + betac[t];
    }
}

// ---------------- k3f: fused GEMM + contact epilogue, one 128-pair tile per block (grid 2048) ----------------
__global__ __launch_bounds__(256, 2) void k3f_gemm(const float* __restrict__ U, const float* __restrict__ V,
        const ushort* __restrict__ wB,
        const float* __restrict__ scale1, const float* __restrict__ shift1,
        const float* __restrict__ Af, const float* __restrict__ Bf2,
        const float* __restrict__ Wc2, const float* __restrict__ bc2,
        const float* __restrict__ posl, const float* __restrict__ posr,
        float* __restrict__ outc, float* __restrict__ outt) {
    __shared__ ushort hT[128 * LDH];     // 34816 B
    __shared__ float part[4][128];       // 2048 B -> 36.9 KB => 4 blocks/CU
    int bid = blockIdx.x, t = threadIdx.x;
    int bl = bid >> 2, it = bid & 3;
    int w = t >> 6, lane = t & 63, lrow = lane & 15, kgrp = lane >> 4;
    const bf16x8* wBv = (const bf16x8*)wB;
    bf16x8 Bfr[2][4];
    #pragma unroll
    for (int nil = 0; nil < 2; nil++)
        #pragma unroll
        for (int ks = 0; ks < 4; ks++)
            Bfr[nil][ks] = wBv[((w * 2 + nil) * 4 + ks) * 64 + lane];
    float av[2], bv[2], wv[2];
    #pragma unroll
    for (int nil = 0; nil < 2; nil++) {
        int c = w * 32 + nil * 16 + lrow;
        av[nil] = Af[c]; bv[nil] = Bf2[c]; wv[nil] = Wc2[c];
    }
    float bc2v = bc2[0];
    int c8 = (t & 15) * 8, rg = t >> 4;
    float4 sc0 = *(const float4*)&scale1[c8], sc1 = *(const float4*)&scale1[c8 + 4];
    float4 sh0 = *(const float4*)&shift1[c8], sh1 = *(const float4*)&shift1[c8 + 4];
    float4 u0 = *(const float4*)&U[bl * HID + c8];
    float4 u1 = *(const float4*)&U[bl * HID + c8 + 4];
    float4 ub0, ub1;
    ub0.x = fmaf(u0.x, sc0.x, sh0.x); ub0.y = fmaf(u0.y, sc0.y, sh0.y);
    ub0.z = fmaf(u0.z, sc0.z, sh0.z); ub0.w = fmaf(u0.w, sc0.w, sh0.w);
    ub1.x = fmaf(u1.x, sc1.x, sh1.x); ub1.y = fmaf(u1.y, sc1.y, sh1.y);
    ub1.z = fmaf(u1.z, sc1.z, sh1.z); ub1.w = fmaf(u1.w, sc1.w, sh1.w);
    int vtile = ((bl >> 6) << 9) + it * 128;
    // stage h tile
    #pragma unroll
    for (int rr = rg; rr < 128; rr += 16) {
        const float* vp = &V[(vtile + rr) * HID + c8];
        float4 v0 = *(const float4*)vp, v1 = *(const float4*)(vp + 4);
        union { bf16x8 v; ushort u[8]; } o;
        o.u[0] = f2bf(elu1(fmaf(v0.x, sc0.x, ub0.x)));
        o.u[1] = f2bf(elu1(fmaf(v0.y, sc0.y, ub0.y)));
        o.u[2] = f2bf(elu1(fmaf(v0.z, sc0.z, ub0.z)));
        o.u[3] = f2bf(elu1(fmaf(v0.w, sc0.w, ub0.w)));
        o.u[4] = f2bf(elu1(fmaf(v1.x, sc1.x, ub1.x)));
        o.u[5] = f2bf(elu1(fmaf(v1.y, sc1.y, ub1.y)));
        o.u[6] = f2bf(elu1(fmaf(v1.z, sc1.z, ub1.z)));
        o.u[7] = f2bf(elu1(fmaf(v1.w, sc1.w, ub1.w)));
        *(bf16x8*)&hT[rr * LDH + c8] = o.v;
    }
    __syncthreads();
    f32x4 acc[8][2];
    #pragma unroll
    for (int m = 0; m < 8; m++) { acc[m][0] = (f32x4){0,0,0,0}; acc[m][1] = (f32x4){0,0,0,0}; }
    #pragma unroll
    for (int m = 0; m < 8; m++) {
        #pragma unroll
        for (int ks = 0; ks < 4; ks++) {
            bf16x8 a = *(const bf16x8*)&hT[(m * 16 + lrow) * LDH + ks * 32 + kgrp * 8];
            acc[m][0] = __builtin_amdgcn_mfma_f32_16x16x32_bf16(a, Bfr[0][ks], acc[m][0], 0, 0, 0);
            acc[m][1] = __builtin_amdgcn_mfma_f32_16x16x32_bf16(a, Bfr[1][ks], acc[m][1], 0, 0, 0);
        }
    }
    // fused epilogue: relu(acc*Af + Bf2)·Wc2, per-wave partial, 16-lane shfl reduce
    #pragma unroll
    for (int reg = 0; reg < 4; reg++) {
        float pr[8];
        #pragma unroll
        for (int m = 0; m < 8; m++) pr[m] = 0.f;
        #pragma unroll
        for (int nil = 0; nil < 2; nil++)
            #pragma unroll
            for (int m = 0; m < 8; m++) {
                float x = fmaf(acc[m][nil][reg], av[nil], bv[nil]);
                pr[m] += fmaxf(x, 0.f) * wv[nil];
            }
        #pragma unroll
        for (int m = 0; m < 8; m++) {
            pr[m] += __shfl_xor(pr[m], 1); pr[m] += __shfl_xor(pr[m], 2);
            pr[m] += __shfl_xor(pr[m], 4); pr[m] += __shfl_xor(pr[m], 8);
        }
        if (lrow == 0) {
            #pragma unroll
            for (int m = 0; m < 8; m++) part[w][m * 16 + kgrp * 4 + reg] = pr[m];
        }
    }
    __syncthreads();
    if (t < 128) {
        int row = bid * 128 + t;
        outc[row] = part[0][t] + part[1][t] + part[2][t] + part[3][t] + bc2v;
        int pbl = row >> 9, pb = row >> 15, pr_ = row & 511;
        float dx = posl[pbl * 3]     - posr[(pb * NR + pr_) * 3];
        float dy = posl[pbl * 3 + 1] - posr[(pb * NR + pr_) * 3 + 1];
        float dz = posl[pbl * 3 + 2] - posr[(pb * NR + pr_) * 3 + 2];
        float y = sqrtf(dx * dx + dy * dy + dz * dz);
        outt[row] = (y < 8.0f) ? 1.0f : 0.0f;
    }
}

extern "C" void kernel_launch(void* const* d_in, const int* in_sizes, int n_in,
                              void* d_out, int out_size, void* d_ws, size_t ws_size,
                              hipStream_t stream) {
    const float* flig  = (const float*)d_in[0];
    const float* posl  = (const float*)d_in[1];
    const float* frec  = (const float*)d_in[3];
    const float* posr  = (const float*)d_in[4];
    const int*   mask  = (const int*)d_in[6];
    const float* W1    = (const float*)d_in[7];
    const float* b1    = (const float*)d_in[8];
    const float* g1    = (const float*)d_in[9];
    const float* beta1 = (const float*)d_in[10];
    const float* Wpi   = (const float*)d_in[11];
    const float* bpi   = (const float*)d_in[12];
    const float* Wsig  = (const float*)d_in[13];
    const float* bsig  = (const float*)d_in[14];
    const float* Wmu   = (const float*)d_in[15];
    const float* bmu   = (const float*)d_in[16];
    const float* Wc1   = (const float*)d_in[17];
    const float* bc1   = (const float*)d_in[18];
    const float* gc    = (const float*)d_in[19];
    const float* betac = (const float*)d_in[20];
    const float* Wc2   = (const float*)d_in[21];
    const float* bc2   = (const float*)d_in[22];

    float* ws = (float*)d_ws;
    float* U      = ws;                 // 65536
    float* V      = ws + 65536;         // 524288 (end 589824)
    float* scale1 = ws + 589824;        // 128
    float* shift1 = ws + 589952;
    float* Af     = ws + 590080;
    float* Bf2    = ws + 590208;        // (end 590336)
    ushort* wB    = (ushort*)(ws + 590336);   // 16384 bf16 = 8192 f (end 598528)
    ushort* wBg   = (ushort*)(ws + 598528);   // 4096 bf16 = 2048 f (end 600576)
    float* bn2s   = ws + 600576;        // 256*128 = 32768 (end 633344)
    float* bn2s2  = ws + 633344;        // (end 666112)
    float* psum   = ws + 666112;        // 8192 (end 674304)
    float* pcnt   = ws + 674304;        // (end 682496)
    float* partS  = ws + 682496;        // 576*128 = 73728 (end 756224)
    float* partS2 = ws + 756224;        // (end 829952)

    float* out = (float*)d_out;
    float* out_logpi   = out;
    float* out_sigma   = out + 1310720;
    float* out_mu      = out + 2621440;
    float* out_prob    = out + 3932160;
    float* out_contact = out + 3932168;
    float* out_truth   = out + 4194312;

    k1_uv<<<dim3(704), dim3(128), 0, stream>>>(flig, frec, W1, b1, Wc1, Wpi, Wsig, Wmu,
        U, V, partS, partS2, wB, wBg);
    k2_bn1<<<dim3(1), dim3(1024), 0, stream>>>(partS, partS2, g1, beta1, scale1, shift1);
    k_sg<<<dim3(1280), dim3(256), 0, stream>>>(mask, U, V, scale1, shift1, wB, wBg, bc1,
        bpi, bsig, bmu, posl, posr, out_logpi, out_sigma, out_mu, psum, pcnt, bn2s, bn2s2);
    k4_bn2<<<dim3(1), dim3(1024), 0, stream>>>(bn2s, bn2s2, gc, betac, bc1, psum, pcnt, Af, Bf2, out_prob);
    k3f_gemm<<<dim3(2048), dim3(256), 0, stream>>>(U, V, wB, scale1, shift1, Af, Bf2, Wc2, bc2,
        posl, posr, out_contact, out_truth);
}

// Round 15
// 88.077 us; speedup vs baseline: 1.2800x; 1.0536x over previous
//
#include <hip/hip_runtime.h>
#include <math.h>

#define B_ 8
#define NL 64
#define NR 512
#define FD 128
#define HID 128
#define KM 10
#define P_ 262144
#define NSAMP 32768
#define M_ 131072
#define LDH 136   // padded LDS row stride in bf16 elems (272B, breaks bank conflicts)

typedef short bf16x8 __attribute__((ext_vector_type(8)));
typedef float f32x4 __attribute__((ext_vector_type(4)));

static __device__ __forceinline__ ushort f2bf(float x) {
    union { float f; unsigned int u; } v; v.f = x;
    unsigned int r = v.u + 0x7FFFu + ((v.u >> 16) & 1u);
    return (ushort)(r >> 16);
}
static __device__ __forceinline__ float elu1(float x) {
    return x > 0.f ? x : (__expf(x) - 1.f);
}

// ---------------- k1: U/V GEMM + col partials; blocks >=576 do weight pre-swizzle ----------------
__global__ __launch_bounds__(128) void k1_uv(const float* __restrict__ flig,
        const float* __restrict__ frec, const float* __restrict__ W1, const float* __restrict__ b1,
        const float* __restrict__ Wc1, const float* __restrict__ Wpi,
        const float* __restrict__ Wsig, const float* __restrict__ Wmu,
        float* __restrict__ U, float* __restrict__ V,
        float* __restrict__ partS, float* __restrict__ partS2,
        ushort* __restrict__ wB, ushort* __restrict__ wBg) {
    __shared__ float fr[8][128];
    int bid = blockIdx.x, c = threadIdx.x;
    if (bid >= 576) {   // weight pre-swizzle path (128 blocks x 128 threads = 16384)
        int idx = (bid - 576) * 128 + c;
        {
            int j = idx & 7, lane = (idx >> 3) & 63, ks = (idx >> 9) & 3, ni = idx >> 11;
            int lrow = lane & 15, kgrp = lane >> 4;
            int n = ni * 16 + lrow, k = ks * 32 + kgrp * 8 + j;
            wB[idx] = f2bf(Wc1[k * HID + n]);
        }
        if (idx < 4096) {
            int j = idx & 7, lane = (idx >> 3) & 63, ks = (idx >> 9) & 3, ni = (idx >> 11) & 1;
            int lrow = lane & 15, kgrp = lane >> 4;
            int n = ni * 16 + lrow, k = ks * 32 + kgrp * 8 + j;
            float wv = 0.f;
            if (n < 10) wv = Wpi[k * KM + n];
            else if (n < 20) wv = Wsig[k * KM + (n - 10)];
            else if (n < 30) wv = Wmu[k * KM + (n - 20)];
            wBg[idx] = f2bf(wv);
        }
        return;
    }
    const float* feat; const float* Wb; float* outp; float bias;
    if (bid < 64) {
        int rowbase = bid * 8;
        feat = flig + rowbase * FD; Wb = W1; outp = U + rowbase * HID; bias = b1[c];
    } else {
        int rowbase = (bid - 64) * 8;
        feat = frec + rowbase * FD; Wb = W1 + FD * HID; outp = V + rowbase * HID; bias = 0.f;
    }
    #pragma unroll
    for (int rr = 0; rr < 8; rr++) fr[rr][c] = feat[rr * FD + c];
    __syncthreads();
    float acc[8];
    #pragma unroll
    for (int rr = 0; rr < 8; rr++) acc[rr] = bias;
    #pragma unroll 4
    for (int k = 0; k < FD; k++) {
        float wv = Wb[k * HID + c];
        #pragma unroll
        for (int rr = 0; rr < 8; rr++) acc[rr] += fr[rr][k] * wv;
    }
    float su = 0.f, su2 = 0.f;
    #pragma unroll
    for (int rr = 0; rr < 8; rr++) {
        outp[rr * HID + c] = acc[rr];
        su += acc[rr]; su2 += acc[rr] * acc[rr];
    }
    partS[bid * 128 + c] = su;
    partS2[bid * 128 + c] = su2;
}

// ---------------- k2: fused BN1 stats reduce + finalize (grid 1 x 1024) ----------------
__global__ __launch_bounds__(1024) void k2_bn1(const float* __restrict__ partS, const float* __restrict__ partS2,
        const float* __restrict__ g1, const float* __restrict__ beta1,
        float* __restrict__ scale1, float* __restrict__ shift1) {
    __shared__ float sU[8][128], sU2[8][128], sV[8][128], sV2[8][128];
    int t = threadIdx.x, c = t & 127, b = t >> 7;
    float su = 0.f, su2 = 0.f;
    #pragma unroll
    for (int j = 0; j < 8; j++) { int row = b * 8 + j; su += partS[row * 128 + c]; su2 += partS2[row * 128 + c]; }
    float sv = 0.f, sv2 = 0.f;
    for (int j = 0; j < 64; j++) { int row = 64 + b * 64 + j; sv += partS[row * 128 + c]; sv2 += partS2[row * 128 + c]; }
    sU[b][c] = su; sU2[b][c] = su2; sV[b][c] = sv; sV2[b][c] = sv2;
    __syncthreads();
    if (t < 128) {
        float sum = 0.f, ssq = 0.f;
        #pragma unroll
        for (int bb = 0; bb < 8; bb++) {
            float s_ = sU[bb][t], v_ = sV[bb][t];
            sum += (float)NR * s_ + (float)NL * v_;
            ssq += (float)NR * sU2[bb][t] + 2.f * s_ * v_ + (float)NL * sV2[bb][t];
        }
        float inv = 1.f / (float)P_;
        float mean = sum * inv;
        float var = ssq * inv - mean * mean;
        float sc = g1[t] * rsqrtf(var + 1e-5f);
        scale1[t] = sc; shift1[t] = beta1[t] - mean * sc;
    }
}

// ---------------- k_sg: blocks 0..511 = MDN (256 rows each); 512..767 = sampled BN2 stats ----------------
__global__ __launch_bounds__(256) void k_sg(const int* __restrict__ mask,
        const float* __restrict__ U, const float* __restrict__ V,
        const float* __restrict__ scale1, const float* __restrict__ shift1,
        const ushort* __restrict__ wB, const ushort* __restrict__ wBg, const float* __restrict__ bc1,
        const float* __restrict__ bpi, const float* __restrict__ bsig, const float* __restrict__ bmu,
        const float* __restrict__ posl, const float* __restrict__ posr,
        float* __restrict__ out_logpi, float* __restrict__ out_sigma, float* __restrict__ out_mu,
        float* __restrict__ mdn_psum, float* __restrict__ mdn_pcnt,
        float* __restrict__ bn2s, float* __restrict__ bn2s2) {
    __shared__ ushort hT[256 * LDH];            // 69632 B (stats path uses first 128 rows)
    __shared__ int midx[256];
    __shared__ float mdnv[256];
    __shared__ int mdnb[256];
    __shared__ float psLds[8][8], pcLds[8][8];
    int t = threadIdx.x;
    int w = t >> 6, lane = t & 63, lrow = lane & 15, kgrp = lane >> 4;
    int c8 = (t & 15) * 8, rg = t >> 4;
    float4 sc0 = *(const float4*)&scale1[c8], sc1 = *(const float4*)&scale1[c8 + 4];
    float4 sh0 = *(const float4*)&shift1[c8], sh1 = *(const float4*)&shift1[c8 + 4];

    if (blockIdx.x < 512) {
        // ================= MDN path (256 rows) =================
        float* stageF = (float*)hT;
        float* zl   = stageF;                    // 256*33 = 8448 floats
        float* bufA = stageF + 8448;
        float* bufB = stageF + 11008;
        float* bufC = stageF + 13568;            // ends 16128 floats = 64512 B
        int bid = blockIdx.x;
        int m0 = bid * 256;
        midx[t] = mask[m0 + t];
        __syncthreads();
        #pragma unroll
        for (int rr = rg; rr < 256; rr += 16) {
            int i = midx[rr];
            int bl = i >> 9, b = i >> 15, r = i & 511;
            const float* up = &U[bl * HID + c8];
            const float* vp = &V[(b * NR + r) * HID + c8];
            float4 u0 = *(const float4*)up, u1 = *(const float4*)(up + 4);
            float4 v0 = *(const float4*)vp, v1 = *(const float4*)(vp + 4);
            union { bf16x8 v; ushort u[8]; } o;
            o.u[0] = f2bf(elu1(fmaf(u0.x + v0.x, sc0.x, sh0.x)));
            o.u[1] = f2bf(elu1(fmaf(u0.y + v0.y, sc0.y, sh0.y)));
            o.u[2] = f2bf(elu1(fmaf(u0.z + v0.z, sc0.z, sh0.z)));
            o.u[3] = f2bf(elu1(fmaf(u0.w + v0.w, sc0.w, sh0.w)));
            o.u[4] = f2bf(elu1(fmaf(u1.x + v1.x, sc1.x, sh1.x)));
            o.u[5] = f2bf(elu1(fmaf(u1.y + v1.y, sc1.y, sh1.y)));
            o.u[6] = f2bf(elu1(fmaf(u1.z + v1.z, sc1.z, sh1.z)));
            o.u[7] = f2bf(elu1(fmaf(u1.w + v1.w, sc1.w, sh1.w)));
            *(bf16x8*)&hT[rr * LDH + c8] = o.v;
        }
        __syncthreads();
        int wrow = w * 64;
        f32x4 acc[4][2];
        #pragma unroll
        for (int m = 0; m < 4; m++) { acc[m][0] = (f32x4){0,0,0,0}; acc[m][1] = (f32x4){0,0,0,0}; }
        const bf16x8* wBv = (const bf16x8*)wBg;
        bf16x8 Bg[2][4];
        #pragma unroll
        for (int nil = 0; nil < 2; nil++)
            #pragma unroll
            for (int ks = 0; ks < 4; ks++)
                Bg[nil][ks] = wBv[(nil * 4 + ks) * 64 + lane];
        #pragma unroll
        for (int m = 0; m < 4; m++) {
            #pragma unroll
            for (int ks = 0; ks < 4; ks++) {
                bf16x8 a = *(const bf16x8*)&hT[(wrow + m * 16 + lrow) * LDH + ks * 32 + kgrp * 8];
                acc[m][0] = __builtin_amdgcn_mfma_f32_16x16x32_bf16(a, Bg[0][ks], acc[m][0], 0, 0, 0);
                acc[m][1] = __builtin_amdgcn_mfma_f32_16x16x32_bf16(a, Bg[1][ks], acc[m][1], 0, 0, 0);
            }
        }
        __syncthreads();   // all hT reads done before zl alias writes
        #pragma unroll
        for (int m = 0; m < 4; m++)
            #pragma unroll
            for (int nil = 0; nil < 2; nil++)
                #pragma unroll
                for (int reg = 0; reg < 4; reg++) {
                    int row = wrow + m * 16 + kgrp * 4 + reg;
                    zl[row * 33 + nil * 16 + lrow] = acc[m][nil][reg];
                }
        __syncthreads();
        {
            float zv[30];
            #pragma unroll
            for (int j = 0; j < 30; j++) zv[j] = zl[t * 33 + j];
            float lp[10], mx = -1e30f;
            #pragma unroll
            for (int j = 0; j < 10; j++) { lp[j] = zv[j] + bpi[j]; mx = fmaxf(mx, lp[j]); }
            float se = 0.f;
            #pragma unroll
            for (int j = 0; j < 10; j++) se += __expf(lp[j] - mx);
            float lse = mx + __logf(se);
            #pragma unroll
            for (int j = 0; j < 10; j++) lp[j] -= lse;
            float sg[10], muv[10];
            #pragma unroll
            for (int j = 0; j < 10; j++) sg[j] = elu1(zv[10 + j] + bsig[j]) + 1.1f;
            #pragma unroll
            for (int j = 0; j < 10; j++) muv[j] = elu1(zv[20 + j] + bmu[j]) + 1.0f;
            int i = midx[t];
            int bl = i >> 9, b = i >> 15, r = i & 511;
            float dx = posl[bl * 3]     - posr[(b * NR + r) * 3];
            float dy = posl[bl * 3 + 1] - posr[(b * NR + r) * 3 + 1];
            float dz = posl[bl * 3 + 2] - posr[(b * NR + r) * 3 + 2];
            float y = sqrtf(dx * dx + dy * dy + dz * dz);
            float tt[10], mm = -1e30f;
            #pragma unroll
            for (int j = 0; j < 10; j++) {
                float q = (y - muv[j]) / sg[j];
                float llv = -0.5f * q * q - __logf(sg[j]) - 0.91893853320467274f;
                tt[j] = lp[j] + llv; mm = fmaxf(mm, tt[j]);
            }
            float s2e = 0.f;
            #pragma unroll
            for (int j = 0; j < 10; j++) s2e += __expf(tt[j] - mm);
            float mdn = -(mm + __logf(s2e));
            #pragma unroll
            for (int j = 0; j < 10; j++) { bufA[t * 10 + j] = lp[j]; bufB[t * 10 + j] = sg[j]; bufC[t * 10 + j] = muv[j]; }
            mdnv[t] = mdn; mdnb[t] = b;
        }
        __syncthreads();
        {
            float4* oA = (float4*)&out_logpi[m0 * 10];
            float4* oB = (float4*)&out_sigma[m0 * 10];
            float4* oC = (float4*)&out_mu[m0 * 10];
            const float4* bA = (const float4*)bufA;
            const float4* bB = (const float4*)bufB;
            const float4* bC = (const float4*)bufC;
            #pragma unroll
            for (int i4 = t; i4 < 640; i4 += 256) { oA[i4] = bA[i4]; oB[i4] = bB[i4]; oC[i4] = bC[i4]; }
        }
        if (t < 64) {   // deterministic fixed-order partial sums: 8 chunks x 8 batches
            int bb = t & 7, chunk = t >> 3;
            float s = 0.f; int cnt = 0;
            for (int rr = chunk * 32; rr < chunk * 32 + 32; rr++)
                if (mdnb[rr] == bb) { s += mdnv[rr]; cnt++; }
            psLds[chunk][bb] = s; pcLds[chunk][bb] = (float)cnt;
        }
        __syncthreads();
        if (t < 8) {
            float s = 0.f, cnt = 0.f;
            #pragma unroll
            for (int chunk = 0; chunk < 8; chunk++) { s += psLds[chunk][t]; cnt += pcLds[chunk][t]; }
            mdn_psum[bid * 8 + t] = s; mdn_pcnt[bid * 8 + t] = cnt;
        }
    } else {
        // ================= sampled BN2 stats path: 256 blocks x 1 tile-pair =================
        int bid = blockIdx.x - 512;
        int bl0 = bid * 2, bl1 = bl0 + 1;
        const bf16x8* wBv = (const bf16x8*)wB;
        bf16x8 Bfr[2][4];
        #pragma unroll
        for (int nil = 0; nil < 2; nil++)
            #pragma unroll
            for (int ks = 0; ks < 4; ks++)
                Bfr[nil][ks] = wBv[((w * 2 + nil) * 4 + ks) * 64 + lane];
        float bc1v[2] = { bc1[w * 32 + lrow], bc1[w * 32 + 16 + lrow] };
        float4 uA0 = *(const float4*)&U[bl0 * HID + c8], uA1 = *(const float4*)&U[bl0 * HID + c8 + 4];
        float4 uB0 = *(const float4*)&U[bl1 * HID + c8], uB1 = *(const float4*)&U[bl1 * HID + c8 + 4];
        float4 ubA0, ubA1, ubB0, ubB1;
        ubA0.x = fmaf(uA0.x, sc0.x, sh0.x); ubA0.y = fmaf(uA0.y, sc0.y, sh0.y);
        ubA0.z = fmaf(uA0.z, sc0.z, sh0.z); ubA0.w = fmaf(uA0.w, sc0.w, sh0.w);
        ubA1.x = fmaf(uA1.x, sc1.x, sh1.x); ubA1.y = fmaf(uA1.y, sc1.y, sh1.y);
        ubA1.z = fmaf(uA1.z, sc1.z, sh1.z); ubA1.w = fmaf(uA1.w, sc1.w, sh1.w);
        ubB0.x = fmaf(uB0.x, sc0.x, sh0.x); ubB0.y = fmaf(uB0.y, sc0.y, sh0.y);
        ubB0.z = fmaf(uB0.z, sc0.z, sh0.z); ubB0.w = fmaf(uB0.w, sc0.w, sh0.w);
        ubB1.x = fmaf(uB1.x, sc1.x, sh1.x); ubB1.y = fmaf(uB1.y, sc1.y, sh1.y);
        ubB1.z = fmaf(uB1.z, sc1.z, sh1.z); ubB1.w = fmaf(uB1.w, sc1.w, sh1.w);
        int vbatch = (bl0 >> 6) << 9;
        #pragma unroll
        for (int k = 0; k < 8; k++) {
            int rr = rg + k * 16;
            int j = rr & 63;
            const float* vp = &V[(vbatch + j * 8) * HID + c8];
            float4 v0 = *(const float4*)vp, v1 = *(const float4*)(vp + 4);
            float4 ub0 = (k < 4) ? ubA0 : ubB0;
            float4 ub1 = (k < 4) ? ubA1 : ubB1;
            union { bf16x8 v; ushort u[8]; } o;
            o.u[0] = f2bf(elu1(fmaf(v0.x, sc0.x, ub0.x)));
            o.u[1] = f2bf(elu1(fmaf(v0.y, sc0.y, ub0.y)));
            o.u[2] = f2bf(elu1(fmaf(v0.z, sc0.z, ub0.z)));
            o.u[3] = f2bf(elu1(fmaf(v0.w, sc0.w, ub0.w)));
            o.u[4] = f2bf(elu1(fmaf(v1.x, sc1.x, ub1.x)));
            o.u[5] = f2bf(elu1(fmaf(v1.y, sc1.y, ub1.y)));
            o.u[6] = f2bf(elu1(fmaf(v1.z, sc1.z, ub1.z)));
            o.u[7] = f2bf(elu1(fmaf(v1.w, sc1.w, ub1.w)));
            *(bf16x8*)&hT[rr * LDH + c8] = o.v;
        }
        __syncthreads();
        f32x4 acc[8][2];
        #pragma unroll
        for (int m = 0; m < 8; m++) { acc[m][0] = (f32x4){0,0,0,0}; acc[m][1] = (f32x4){0,0,0,0}; }
        #pragma unroll
        for (int m = 0; m < 8; m++) {
            #pragma unroll
            for (int ks = 0; ks < 4; ks++) {
                bf16x8 a = *(const bf16x8*)&hT[(m * 16 + lrow) * LDH + ks * 32 + kgrp * 8];
                acc[m][0] = __builtin_amdgcn_mfma_f32_16x16x32_bf16(a, Bfr[0][ks], acc[m][0], 0, 0, 0);
                acc[m][1] = __builtin_amdgcn_mfma_f32_16x16x32_bf16(a, Bfr[1][ks], acc[m][1], 0, 0, 0);
            }
        }
        float s[2] = {0.f, 0.f}, s2[2] = {0.f, 0.f};
        #pragma unroll
        for (int nil = 0; nil < 2; nil++)
            #pragma unroll
            for (int reg = 0; reg < 4; reg++)
                #pragma unroll
                for (int m = 0; m < 8; m++) {
                    float vv = acc[m][nil][reg] + bc1v[nil];
                    s[nil] += vv; s2[nil] += vv * vv;
                }
        #pragma unroll
        for (int nil = 0; nil < 2; nil++) {
            s[nil] += __shfl_xor(s[nil], 16);  s[nil] += __shfl_xor(s[nil], 32);
            s2[nil] += __shfl_xor(s2[nil], 16); s2[nil] += __shfl_xor(s2[nil], 32);
        }
        if (lane < 16) {
            bn2s[bid * 128 + w * 32 + lane]       = s[0];
            bn2s[bid * 128 + w * 32 + 16 + lane]  = s[1];
            bn2s2[bid * 128 + w * 32 + lane]      = s2[0];
            bn2s2[bid * 128 + w * 32 + 16 + lane] = s2[1];
        }
    }
}

// ---------------- k4: sampled-BN2 finalize + prob segment-mean (grid 1 x 1024) ----------------
__global__ __launch_bounds__(1024) void k4_bn2(const float* __restrict__ bn2s, const float* __restrict__ bn2s2,
        const float* __restrict__ gc, const float* __restrict__ betac, const float* __restrict__ bc1,
        const float* __restrict__ psum, const float* __restrict__ pcnt,
        float* __restrict__ Af, float* __restrict__ Bf2, float* __restrict__ prob) {
    __shared__ float rs[8][128], rs2[8][128];
    __shared__ float prs[8][128], prc[8][128];
    int t = threadIdx.x, c = t & 127, g = t >> 7;
    float s = 0.f, s2 = 0.f;
    for (int j = 0; j < 32; j++) { int row = g * 32 + j; s += bn2s[row * 128 + c]; s2 += bn2s2[row * 128 + c]; }
    rs[g][c] = s; rs2[g][c] = s2;
    // prob partials: batch g, thread c sums rows c, c+128, c+256, c+384 (512 psum rows)
    float ps = 0.f, pc = 0.f;
    #pragma unroll
    for (int k = 0; k < 4; k++) { int row = c + k * 128; ps += psum[row * 8 + g]; pc += pcnt[row * 8 + g]; }
    prs[g][c] = ps; prc[g][c] = pc;
    __syncthreads();
    for (int off = 64; off > 0; off >>= 1) {
        if (c < off) { prs[g][c] += prs[g][c + off]; prc[g][c] += prc[g][c + off]; }
        __syncthreads();
    }
    if (c == 0) prob[g] = prs[g][0] / fmaxf(prc[g][0], 1.f);
    if (t < 128) {
        float ss = 0.f, ss2 = 0.f;
        #pragma unroll
        for (int gg = 0; gg < 8; gg++) { ss += rs[gg][t]; ss2 += rs2[gg][t]; }
        float inv = 1.f / (float)NSAMP;
        float mean = ss * inv, var = ss2 * inv - mean * mean;
        float sc = gc[t] * rsqrtf(var + 1e-5f);
        Af[t] = sc;
        Bf2[t] = (bc1[t] - mean) * sc + betac[t];
    }
}

// ---------------- k3f: fused GEMM + contact epilogue, one 128-pair tile per block (grid 2048, XCD swizzle) ----------------
__global__ __launch_bounds__(256, 2) void k3f_gemm(const float* __restrict__ U, const float* __restrict__ V,
        const ushort* __restrict__ wB,
        const float* __restrict__ scale1, const float* __restrict__ shift1,
        const float* __restrict__ Af, const float* __restrict__ Bf2,
        const float* __restrict__ Wc2, const float* __restrict__ bc2,
        const float* __restrict__ posl, const float* __restrict__ posr,
        float* __restrict__ outc, float* __restrict__ outt) {
    __shared__ ushort hT[128 * LDH];     // 34816 B
    __shared__ float part[4][128];       // 2048 B -> 36.9 KB => 4 blocks/CU
    int t = threadIdx.x;
    // bijective XCD swizzle (2048 % 8 == 0): each XCD gets a contiguous 256-block chunk
    int bid = (blockIdx.x & 7) * 256 + (blockIdx.x >> 3);
    int bl = bid >> 2, it = bid & 3;
    int w = t >> 6, lane = t & 63, lrow = lane & 15, kgrp = lane >> 4;
    const bf16x8* wBv = (const bf16x8*)wB;
    bf16x8 Bfr[2][4];
    #pragma unroll
    for (int nil = 0; nil < 2; nil++)
        #pragma unroll
        for (int ks = 0; ks < 4; ks++)
            Bfr[nil][ks] = wBv[((w * 2 + nil) * 4 + ks) * 64 + lane];
    float av[2], bv[2], wv[2];
    #pragma unroll
    for (int nil = 0; nil < 2; nil++) {
        int c = w * 32 + nil * 16 + lrow;
        av[nil] = Af[c]; bv[nil] = Bf2[c]; wv[nil] = Wc2[c];
    }
    float bc2v = bc2[0];
    int c8 = (t & 15) * 8, rg = t >> 4;
    float4 sc0 = *(const float4*)&scale1[c8], sc1 = *(const float4*)&scale1[c8 + 4];
    float4 sh0 = *(const float4*)&shift1[c8], sh1 = *(const float4*)&shift1[c8 + 4];
    float4 u0 = *(const float4*)&U[bl * HID + c8];
    float4 u1 = *(const float4*)&U[bl * HID + c8 + 4];
    float4 ub0, ub1;
    ub0.x = fmaf(u0.x, sc0.x, sh0.x); ub0.y = fmaf(u0.y, sc0.y, sh0.y);
    ub0.z = fmaf(u0.z, sc0.z, sh0.z); ub0.w = fmaf(u0.w, sc0.w, sh0.w);
    ub1.x = fmaf(u1.x, sc1.x, sh1.x); ub1.y = fmaf(u1.y, sc1.y, sh1.y);
    ub1.z = fmaf(u1.z, sc1.z, sh1.z); ub1.w = fmaf(u1.w, sc1.w, sh1.w);
    int vtile = ((bl >> 6) << 9) + it * 128;
    // stage h tile
    #pragma unroll
    for (int rr = rg; rr < 128; rr += 16) {
        const float* vp = &V[(vtile + rr) * HID + c8];
        float4 v0 = *(const float4*)vp, v1 = *(const float4*)(vp + 4);
        union { bf16x8 v; ushort u[8]; } o;
        o.u[0] = f2bf(elu1(fmaf(v0.x, sc0.x, ub0.x)));
        o.u[1] = f2bf(elu1(fmaf(v0.y, sc0.y, ub0.y)));
        o.u[2] = f2bf(elu1(fmaf(v0.z, sc0.z, ub0.z)));
        o.u[3] = f2bf(elu1(fmaf(v0.w, sc0.w, ub0.w)));
        o.u[4] = f2bf(elu1(fmaf(v1.x, sc1.x, ub1.x)));
        o.u[5] = f2bf(elu1(fmaf(v1.y, sc1.y, ub1.y)));
        o.u[6] = f2bf(elu1(fmaf(v1.z, sc1.z, ub1.z)));
        o.u[7] = f2bf(elu1(fmaf(v1.w, sc1.w, ub1.w)));
        *(bf16x8*)&hT[rr * LDH + c8] = o.v;
    }
    __syncthreads();
    f32x4 acc[8][2];
    #pragma unroll
    for (int m = 0; m < 8; m++) { acc[m][0] = (f32x4){0,0,0,0}; acc[m][1] = (f32x4){0,0,0,0}; }
    #pragma unroll
    for (int m = 0; m < 8; m++) {
        #pragma unroll
        for (int ks = 0; ks < 4; ks++) {
            bf16x8 a = *(const bf16x8*)&hT[(m * 16 + lrow) * LDH + ks * 32 + kgrp * 8];
            acc[m][0] = __builtin_amdgcn_mfma_f32_16x16x32_bf16(a, Bfr[0][ks], acc[m][0], 0, 0, 0);
            acc[m][1] = __builtin_amdgcn_mfma_f32_16x16x32_bf16(a, Bfr[1][ks], acc[m][1], 0, 0, 0);
        }
    }
    // fused epilogue: relu(acc*Af + Bf2)·Wc2, per-wave partial, 16-lane shfl reduce
    #pragma unroll
    for (int reg = 0; reg < 4; reg++) {
        float pr[8];
        #pragma unroll
        for (int m = 0; m < 8; m++) pr[m] = 0.f;
        #pragma unroll
        for (int nil = 0; nil < 2; nil++)
            #pragma unroll
            for (int m = 0; m < 8; m++) {
                float x = fmaf(acc[m][nil][reg], av[nil], bv[nil]);
                pr[m] += fmaxf(x, 0.f) * wv[nil];
            }
        #pragma unroll
        for (int m = 0; m < 8; m++) {
            pr[m] += __shfl_xor(pr[m], 1); pr[m] += __shfl_xor(pr[m], 2);
            pr[m] += __shfl_xor(pr[m], 4); pr[m] += __shfl_xor(pr[m], 8);
        }
        if (lrow == 0) {
            #pragma unroll
            for (int m = 0; m < 8; m++) part[w][m * 16 + kgrp * 4 + reg] = pr[m];
        }
    }
    __syncthreads();
    if (t < 128) {
        int row = bid * 128 + t;
        outc[row] = part[0][t] + part[1][t] + part[2][t] + part[3][t] + bc2v;
        int pbl = row >> 9, pb = row >> 15, pr_ = row & 511;
        float dx = posl[pbl * 3]     - posr[(pb * NR + pr_) * 3];
        float dy = posl[pbl * 3 + 1] - posr[(pb * NR + pr_) * 3 + 1];
        float dz = posl[pbl * 3 + 2] - posr[(pb * NR + pr_) * 3 + 2];
        float y = sqrtf(dx * dx + dy * dy + dz * dz);
        outt[row] = (y < 8.0f) ? 1.0f : 0.0f;
    }
}

extern "C" void kernel_launch(void* const* d_in, const int* in_sizes, int n_in,
                              void* d_out, int out_size, void* d_ws, size_t ws_size,
                              hipStream_t stream) {
    const float* flig  = (const float*)d_in[0];
    const float* posl  = (const float*)d_in[1];
    const float* frec  = (const float*)d_in[3];
    const float* posr  = (const float*)d_in[4];
    const int*   mask  = (const int*)d_in[6];
    const float* W1    = (const float*)d_in[7];
    const float* b1    = (const float*)d_in[8];
    const float* g1    = (const float*)d_in[9];
    const float* beta1 = (const float*)d_in[10];
    const float* Wpi   = (const float*)d_in[11];
    const float* bpi   = (const float*)d_in[12];
    const float* Wsig  = (const float*)d_in[13];
    const float* bsig  = (const float*)d_in[14];
    const float* Wmu   = (const float*)d_in[15];
    const float* bmu   = (const float*)d_in[16];
    const float* Wc1   = (const float*)d_in[17];
    const float* bc1   = (const float*)d_in[18];
    const float* gc    = (const float*)d_in[19];
    const float* betac = (const float*)d_in[20];
    const float* Wc2   = (const float*)d_in[21];
    const float* bc2   = (const float*)d_in[22];

    float* ws = (float*)d_ws;
    float* U      = ws;                 // 65536
    float* V      = ws + 65536;         // 524288 (end 589824)
    float* scale1 = ws + 589824;        // 128
    float* shift1 = ws + 589952;
    float* Af     = ws + 590080;
    float* Bf2    = ws + 590208;        // (end 590336)
    ushort* wB    = (ushort*)(ws + 590336);   // 16384 bf16 = 8192 f (end 598528)
    ushort* wBg   = (ushort*)(ws + 598528);   // 4096 bf16 = 2048 f (end 600576)
    float* bn2s   = ws + 600576;        // 256*128 = 32768 (end 633344)
    float* bn2s2  = ws + 633344;        // (end 666112)
    float* psum   = ws + 666112;        // 4096 (end 670208)
    float* pcnt   = ws + 670208;        // (end 674304)
    float* partS  = ws + 674304;        // 576*128 = 73728 (end 748032)
    float* partS2 = ws + 748032;        // (end 821760)

    float* out = (float*)d_out;
    float* out_logpi   = out;
    float* out_sigma   = out + 1310720;
    float* out_mu      = out + 2621440;
    float* out_prob    = out + 3932160;
    float* out_contact = out + 3932168;
    float* out_truth   = out + 4194312;

    k1_uv<<<dim3(704), dim3(128), 0, stream>>>(flig, frec, W1, b1, Wc1, Wpi, Wsig, Wmu,
        U, V, partS, partS2, wB, wBg);
    k2_bn1<<<dim3(1), dim3(1024), 0, stream>>>(partS, partS2, g1, beta1, scale1, shift1);
    k_sg<<<dim3(768), dim3(256), 0, stream>>>(mask, U, V, scale1, shift1, wB, wBg, bc1,
        bpi, bsig, bmu, posl, posr, out_logpi, out_sigma, out_mu, psum, pcnt, bn2s, bn2s2);
    k4_bn2<<<dim3(1), dim3(1024), 0, stream>>>(bn2s, bn2s2, gc, betac, bc1, psum, pcnt, Af, Bf2, out_prob);
    k3f_gemm<<<dim3(2048), dim3(256), 0, stream>>>(U, V, wB, scale1, shift1, Af, Bf2, Wc2, bc2,
        posl, posr, out_contact, out_truth);
}

// Round 16
// 83.464 us; speedup vs baseline: 1.3507x; 1.0553x over previous
//
#include <hip/hip_runtime.h>
#include <math.h>

#define B_ 8
#define NL 64
#define NR 512
#define FD 128
#define HID 128
#define KM 10
#define P_ 262144
#define NSAMP 32768
#define M_ 131072
#define LDH 136   // padded LDS row stride in bf16 elems (272B, breaks bank conflicts)

typedef short bf16x8 __attribute__((ext_vector_type(8)));
typedef float f32x4 __attribute__((ext_vector_type(4)));

static __device__ __forceinline__ ushort f2bf(float x) {
    union { float f; unsigned int u; } v; v.f = x;
    unsigned int r = v.u + 0x7FFFu + ((v.u >> 16) & 1u);
    return (ushort)(r >> 16);
}
static __device__ __forceinline__ float elu1(float x) {
    return x > 0.f ? x : (__expf(x) - 1.f);
}

// ---------------- k1: U/V GEMM + col partials; blocks >=576 do weight pre-swizzle ----------------
__global__ __launch_bounds__(128) void k1_uv(const float* __restrict__ flig,
        const float* __restrict__ frec, const float* __restrict__ W1, const float* __restrict__ b1,
        const float* __restrict__ Wc1, const float* __restrict__ Wpi,
        const float* __restrict__ Wsig, const float* __restrict__ Wmu,
        float* __restrict__ U, float* __restrict__ V,
        float* __restrict__ partS, float* __restrict__ partS2,
        ushort* __restrict__ wB, ushort* __restrict__ wBg) {
    __shared__ float fr[8][128];
    int bid = blockIdx.x, c = threadIdx.x;
    if (bid >= 576) {   // weight pre-swizzle path (128 blocks x 128 threads = 16384)
        int idx = (bid - 576) * 128 + c;
        {
            int j = idx & 7, lane = (idx >> 3) & 63, ks = (idx >> 9) & 3, ni = idx >> 11;
            int lrow = lane & 15, kgrp = lane >> 4;
            int n = ni * 16 + lrow, k = ks * 32 + kgrp * 8 + j;
            wB[idx] = f2bf(Wc1[k * HID + n]);
        }
        if (idx < 4096) {
            int j = idx & 7, lane = (idx >> 3) & 63, ks = (idx >> 9) & 3, ni = (idx >> 11) & 1;
            int lrow = lane & 15, kgrp = lane >> 4;
            int n = ni * 16 + lrow, k = ks * 32 + kgrp * 8 + j;
            float wv = 0.f;
            if (n < 10) wv = Wpi[k * KM + n];
            else if (n < 20) wv = Wsig[k * KM + (n - 10)];
            else if (n < 30) wv = Wmu[k * KM + (n - 20)];
            wBg[idx] = f2bf(wv);
        }
        return;
    }
    const float* feat; const float* Wb; float* outp; float bias;
    if (bid < 64) {
        int rowbase = bid * 8;
        feat = flig + rowbase * FD; Wb = W1; outp = U + rowbase * HID; bias = b1[c];
    } else {
        int rowbase = (bid - 64) * 8;
        feat = frec + rowbase * FD; Wb = W1 + FD * HID; outp = V + rowbase * HID; bias = 0.f;
    }
    #pragma unroll
    for (int rr = 0; rr < 8; rr++) fr[rr][c] = feat[rr * FD + c];
    __syncthreads();
    float acc[8];
    #pragma unroll
    for (int rr = 0; rr < 8; rr++) acc[rr] = bias;
    #pragma unroll 4
    for (int k = 0; k < FD; k++) {
        float wv = Wb[k * HID + c];
        #pragma unroll
        for (int rr = 0; rr < 8; rr++) acc[rr] += fr[rr][k] * wv;
    }
    float su = 0.f, su2 = 0.f;
    #pragma unroll
    for (int rr = 0; rr < 8; rr++) {
        outp[rr * HID + c] = acc[rr];
        su += acc[rr]; su2 += acc[rr] * acc[rr];
    }
    partS[bid * 128 + c] = su;
    partS2[bid * 128 + c] = su2;
}

// ---------------- k2: fused BN1 stats reduce + finalize (grid 1 x 1024) ----------------
__global__ __launch_bounds__(1024) void k2_bn1(const float* __restrict__ partS, const float* __restrict__ partS2,
        const float* __restrict__ g1, const float* __restrict__ beta1,
        float* __restrict__ scale1, float* __restrict__ shift1) {
    __shared__ float sU[8][128], sU2[8][128], sV[8][128], sV2[8][128];
    int t = threadIdx.x, c = t & 127, b = t >> 7;
    float su = 0.f, su2 = 0.f;
    #pragma unroll
    for (int j = 0; j < 8; j++) { int row = b * 8 + j; su += partS[row * 128 + c]; su2 += partS2[row * 128 + c]; }
    float sv = 0.f, sv2 = 0.f;
    for (int j = 0; j < 64; j++) { int row = 64 + b * 64 + j; sv += partS[row * 128 + c]; sv2 += partS2[row * 128 + c]; }
    sU[b][c] = su; sU2[b][c] = su2; sV[b][c] = sv; sV2[b][c] = sv2;
    __syncthreads();
    if (t < 128) {
        float sum = 0.f, ssq = 0.f;
        #pragma unroll
        for (int bb = 0; bb < 8; bb++) {
            float s_ = sU[bb][t], v_ = sV[bb][t];
            sum += (float)NR * s_ + (float)NL * v_;
            ssq += (float)NR * sU2[bb][t] + 2.f * s_ * v_ + (float)NL * sV2[bb][t];
        }
        float inv = 1.f / (float)P_;
        float mean = sum * inv;
        float var = ssq * inv - mean * mean;
        float sc = g1[t] * rsqrtf(var + 1e-5f);
        scale1[t] = sc; shift1[t] = beta1[t] - mean * sc;
    }
}

// ---------------- k_stats: sampled BN2 stats (256 blocks x 1 tile-pair) ----------------
__global__ __launch_bounds__(256, 2) void k_stats(const float* __restrict__ U, const float* __restrict__ V,
        const float* __restrict__ scale1, const float* __restrict__ shift1,
        const ushort* __restrict__ wB, const float* __restrict__ bc1,
        float* __restrict__ bn2s, float* __restrict__ bn2s2) {
    __shared__ ushort hT[128 * LDH];
    int bid = blockIdx.x, t = threadIdx.x;
    int w = t >> 6, lane = t & 63, lrow = lane & 15, kgrp = lane >> 4;
    int c8 = (t & 15) * 8, rg = t >> 4;
    float4 sc0 = *(const float4*)&scale1[c8], sc1 = *(const float4*)&scale1[c8 + 4];
    float4 sh0 = *(const float4*)&shift1[c8], sh1 = *(const float4*)&shift1[c8 + 4];
    int bl0 = bid * 2, bl1 = bl0 + 1;
    const bf16x8* wBv = (const bf16x8*)wB;
    bf16x8 Bfr[2][4];
    #pragma unroll
    for (int nil = 0; nil < 2; nil++)
        #pragma unroll
        for (int ks = 0; ks < 4; ks++)
            Bfr[nil][ks] = wBv[((w * 2 + nil) * 4 + ks) * 64 + lane];
    float bc1v[2] = { bc1[w * 32 + lrow], bc1[w * 32 + 16 + lrow] };
    float4 uA0 = *(const float4*)&U[bl0 * HID + c8], uA1 = *(const float4*)&U[bl0 * HID + c8 + 4];
    float4 uB0 = *(const float4*)&U[bl1 * HID + c8], uB1 = *(const float4*)&U[bl1 * HID + c8 + 4];
    float4 ubA0, ubA1, ubB0, ubB1;
    ubA0.x = fmaf(uA0.x, sc0.x, sh0.x); ubA0.y = fmaf(uA0.y, sc0.y, sh0.y);
    ubA0.z = fmaf(uA0.z, sc0.z, sh0.z); ubA0.w = fmaf(uA0.w, sc0.w, sh0.w);
    ubA1.x = fmaf(uA1.x, sc1.x, sh1.x); ubA1.y = fmaf(uA1.y, sc1.y, sh1.y);
    ubA1.z = fmaf(uA1.z, sc1.z, sh1.z); ubA1.w = fmaf(uA1.w, sc1.w, sh1.w);
    ubB0.x = fmaf(uB0.x, sc0.x, sh0.x); ubB0.y = fmaf(uB0.y, sc0.y, sh0.y);
    ubB0.z = fmaf(uB0.z, sc0.z, sh0.z); ubB0.w = fmaf(uB0.w, sc0.w, sh0.w);
    ubB1.x = fmaf(uB1.x, sc1.x, sh1.x); ubB1.y = fmaf(uB1.y, sc1.y, sh1.y);
    ubB1.z = fmaf(uB1.z, sc1.z, sh1.z); ubB1.w = fmaf(uB1.w, sc1.w, sh1.w);
    int vbatch = (bl0 >> 6) << 9;
    #pragma unroll
    for (int k = 0; k < 8; k++) {
        int rr = rg + k * 16;
        int j = rr & 63;
        const float* vp = &V[(vbatch + j * 8) * HID + c8];
        float4 v0 = *(const float4*)vp, v1 = *(const float4*)(vp + 4);
        float4 ub0 = (k < 4) ? ubA0 : ubB0;
        float4 ub1 = (k < 4) ? ubA1 : ubB1;
        union { bf16x8 v; ushort u[8]; } o;
        o.u[0] = f2bf(elu1(fmaf(v0.x, sc0.x, ub0.x)));
        o.u[1] = f2bf(elu1(fmaf(v0.y, sc0.y, ub0.y)));
        o.u[2] = f2bf(elu1(fmaf(v0.z, sc0.z, ub0.z)));
        o.u[3] = f2bf(elu1(fmaf(v0.w, sc0.w, ub0.w)));
        o.u[4] = f2bf(elu1(fmaf(v1.x, sc1.x, ub1.x)));
        o.u[5] = f2bf(elu1(fmaf(v1.y, sc1.y, ub1.y)));
        o.u[6] = f2bf(elu1(fmaf(v1.z, sc1.z, ub1.z)));
        o.u[7] = f2bf(elu1(fmaf(v1.w, sc1.w, ub1.w)));
        *(bf16x8*)&hT[rr * LDH + c8] = o.v;
    }
    __syncthreads();
    f32x4 acc[8][2];
    #pragma unroll
    for (int m = 0; m < 8; m++) { acc[m][0] = (f32x4){0,0,0,0}; acc[m][1] = (f32x4){0,0,0,0}; }
    #pragma unroll
    for (int m = 0; m < 8; m++) {
        #pragma unroll
        for (int ks = 0; ks < 4; ks++) {
            bf16x8 a = *(const bf16x8*)&hT[(m * 16 + lrow) * LDH + ks * 32 + kgrp * 8];
            acc[m][0] = __builtin_amdgcn_mfma_f32_16x16x32_bf16(a, Bfr[0][ks], acc[m][0], 0, 0, 0);
            acc[m][1] = __builtin_amdgcn_mfma_f32_16x16x32_bf16(a, Bfr[1][ks], acc[m][1], 0, 0, 0);
        }
    }
    float s[2] = {0.f, 0.f}, s2[2] = {0.f, 0.f};
    #pragma unroll
    for (int nil = 0; nil < 2; nil++)
        #pragma unroll
        for (int reg = 0; reg < 4; reg++)
            #pragma unroll
            for (int m = 0; m < 8; m++) {
                float vv = acc[m][nil][reg] + bc1v[nil];
                s[nil] += vv; s2[nil] += vv * vv;
            }
    #pragma unroll
    for (int nil = 0; nil < 2; nil++) {
        s[nil] += __shfl_xor(s[nil], 16);  s[nil] += __shfl_xor(s[nil], 32);
        s2[nil] += __shfl_xor(s2[nil], 16); s2[nil] += __shfl_xor(s2[nil], 32);
    }
    if (lane < 16) {
        bn2s[bid * 128 + w * 32 + lane]       = s[0];
        bn2s[bid * 128 + w * 32 + 16 + lane]  = s[1];
        bn2s2[bid * 128 + w * 32 + lane]      = s2[0];
        bn2s2[bid * 128 + w * 32 + 16 + lane] = s2[1];
    }
}

// ---------------- k4: sampled-BN2 finalize + prob segment-mean (grid 1 x 1024) ----------------
__global__ __launch_bounds__(1024) void k4_bn2(const float* __restrict__ bn2s, const float* __restrict__ bn2s2,
        const float* __restrict__ gc, const float* __restrict__ betac, const float* __restrict__ bc1,
        float* __restrict__ Af, float* __restrict__ Bf2) {
    __shared__ float rs[8][128], rs2[8][128];
    int t = threadIdx.x, c = t & 127, g = t >> 7;
    float s = 0.f, s2 = 0.f;
    for (int j = 0; j < 32; j++) { int row = g * 32 + j; s += bn2s[row * 128 + c]; s2 += bn2s2[row * 128 + c]; }
    rs[g][c] = s; rs2[g][c] = s2;
    __syncthreads();
    if (t < 128) {
        float ss = 0.f, ss2 = 0.f;
        #pragma unroll
        for (int gg = 0; gg < 8; gg++) { ss += rs[gg][t]; ss2 += rs2[gg][t]; }
        float inv = 1.f / (float)NSAMP;
        float mean = ss * inv, var = ss2 * inv - mean * mean;
        float sc = gc[t] * rsqrtf(var + 1e-5f);
        Af[t] = sc;
        Bf2[t] = (bc1[t] - mean) * sc + betac[t];
    }
}

// ---------------- k_mix: 3072 blocks — pattern of 3: {2x contact tile, 1x MDN-128} ----------------
__global__ __launch_bounds__(256, 2) void k_mix(const int* __restrict__ mask,
        const float* __restrict__ U, const float* __restrict__ V,
        const float* __restrict__ scale1, const float* __restrict__ shift1,
        const ushort* __restrict__ wB, const ushort* __restrict__ wBg,
        const float* __restrict__ Af, const float* __restrict__ Bf2,
        const float* __restrict__ Wc2, const float* __restrict__ bc2,
        const float* __restrict__ bpi, const float* __restrict__ bsig, const float* __restrict__ bmu,
        const float* __restrict__ posl, const float* __restrict__ posr,
        float* __restrict__ outc, float* __restrict__ outt,
        float* __restrict__ out_logpi, float* __restrict__ out_sigma, float* __restrict__ out_mu,
        float* __restrict__ mdn_psum, float* __restrict__ mdn_pcnt) {
    __shared__ ushort hT[128 * LDH];     // 34816 B
    __shared__ float part[4][128];       // 2048 B
    __shared__ int midx[128];
    __shared__ float mdnv[128];
    __shared__ int mdnb[128];
    __shared__ float psLds[8][8], pcLds[8][8];   // total ~38.9 KB => 4 blocks/CU
    int t = threadIdx.x;
    int bid3 = blockIdx.x;
    int phase = bid3 % 3;
    int w = t >> 6, lane = t & 63, lrow = lane & 15, kgrp = lane >> 4;
    int c8 = (t & 15) * 8, rg = t >> 4;
    float4 sc0 = *(const float4*)&scale1[c8], sc1 = *(const float4*)&scale1[c8 + 4];
    float4 sh0 = *(const float4*)&shift1[c8], sh1 = *(const float4*)&shift1[c8 + 4];

    if (phase < 2) {
        // ================= contact tile path =================
        int k3 = (bid3 / 3) * 2 + phase;                 // 0..2047
        int bid = (k3 & 7) * 256 + (k3 >> 3);            // bijective XCD-chunk swizzle
        int bl = bid >> 2, it = bid & 3;
        const bf16x8* wBv = (const bf16x8*)wB;
        bf16x8 Bfr[2][4];
        #pragma unroll
        for (int nil = 0; nil < 2; nil++)
            #pragma unroll
            for (int ks = 0; ks < 4; ks++)
                Bfr[nil][ks] = wBv[((w * 2 + nil) * 4 + ks) * 64 + lane];
        float av[2], bv[2], wv[2];
        #pragma unroll
        for (int nil = 0; nil < 2; nil++) {
            int c = w * 32 + nil * 16 + lrow;
            av[nil] = Af[c]; bv[nil] = Bf2[c]; wv[nil] = Wc2[c];
        }
        float bc2v = bc2[0];
        float4 u0 = *(const float4*)&U[bl * HID + c8];
        float4 u1 = *(const float4*)&U[bl * HID + c8 + 4];
        float4 ub0, ub1;
        ub0.x = fmaf(u0.x, sc0.x, sh0.x); ub0.y = fmaf(u0.y, sc0.y, sh0.y);
        ub0.z = fmaf(u0.z, sc0.z, sh0.z); ub0.w = fmaf(u0.w, sc0.w, sh0.w);
        ub1.x = fmaf(u1.x, sc1.x, sh1.x); ub1.y = fmaf(u1.y, sc1.y, sh1.y);
        ub1.z = fmaf(u1.z, sc1.z, sh1.z); ub1.w = fmaf(u1.w, sc1.w, sh1.w);
        int vtile = ((bl >> 6) << 9) + it * 128;
        #pragma unroll
        for (int rr = rg; rr < 128; rr += 16) {
            const float* vp = &V[(vtile + rr) * HID + c8];
            float4 v0 = *(const float4*)vp, v1 = *(const float4*)(vp + 4);
            union { bf16x8 v; ushort u[8]; } o;
            o.u[0] = f2bf(elu1(fmaf(v0.x, sc0.x, ub0.x)));
            o.u[1] = f2bf(elu1(fmaf(v0.y, sc0.y, ub0.y)));
            o.u[2] = f2bf(elu1(fmaf(v0.z, sc0.z, ub0.z)));
            o.u[3] = f2bf(elu1(fmaf(v0.w, sc0.w, ub0.w)));
            o.u[4] = f2bf(elu1(fmaf(v1.x, sc1.x, ub1.x)));
            o.u[5] = f2bf(elu1(fmaf(v1.y, sc1.y, ub1.y)));
            o.u[6] = f2bf(elu1(fmaf(v1.z, sc1.z, ub1.z)));
            o.u[7] = f2bf(elu1(fmaf(v1.w, sc1.w, ub1.w)));
            *(bf16x8*)&hT[rr * LDH + c8] = o.v;
        }
        __syncthreads();
        f32x4 acc[8][2];
        #pragma unroll
        for (int m = 0; m < 8; m++) { acc[m][0] = (f32x4){0,0,0,0}; acc[m][1] = (f32x4){0,0,0,0}; }
        #pragma unroll
        for (int m = 0; m < 8; m++) {
            #pragma unroll
            for (int ks = 0; ks < 4; ks++) {
                bf16x8 a = *(const bf16x8*)&hT[(m * 16 + lrow) * LDH + ks * 32 + kgrp * 8];
                acc[m][0] = __builtin_amdgcn_mfma_f32_16x16x32_bf16(a, Bfr[0][ks], acc[m][0], 0, 0, 0);
                acc[m][1] = __builtin_amdgcn_mfma_f32_16x16x32_bf16(a, Bfr[1][ks], acc[m][1], 0, 0, 0);
            }
        }
        #pragma unroll
        for (int reg = 0; reg < 4; reg++) {
            float pr[8];
            #pragma unroll
            for (int m = 0; m < 8; m++) pr[m] = 0.f;
            #pragma unroll
            for (int nil = 0; nil < 2; nil++)
                #pragma unroll
                for (int m = 0; m < 8; m++) {
                    float x = fmaf(acc[m][nil][reg], av[nil], bv[nil]);
                    pr[m] += fmaxf(x, 0.f) * wv[nil];
                }
            #pragma unroll
            for (int m = 0; m < 8; m++) {
                pr[m] += __shfl_xor(pr[m], 1); pr[m] += __shfl_xor(pr[m], 2);
                pr[m] += __shfl_xor(pr[m], 4); pr[m] += __shfl_xor(pr[m], 8);
            }
            if (lrow == 0) {
                #pragma unroll
                for (int m = 0; m < 8; m++) part[w][m * 16 + kgrp * 4 + reg] = pr[m];
            }
        }
        __syncthreads();
        if (t < 128) {
            int row = bid * 128 + t;
            outc[row] = part[0][t] + part[1][t] + part[2][t] + part[3][t] + bc2v;
            int pbl = row >> 9, pb = row >> 15, pr_ = row & 511;
            float dx = posl[pbl * 3]     - posr[(pb * NR + pr_) * 3];
            float dy = posl[pbl * 3 + 1] - posr[(pb * NR + pr_) * 3 + 1];
            float dz = posl[pbl * 3 + 2] - posr[(pb * NR + pr_) * 3 + 2];
            float y = sqrtf(dx * dx + dy * dy + dz * dz);
            outt[row] = (y < 8.0f) ? 1.0f : 0.0f;
        }
    } else {
        // ================= MDN path (128 rows) =================
        float* stageF = (float*)hT;
        float* zl   = stageF;                    // 128*33 = 4224 floats
        float* bufA = stageF + 4352;             // 1280 floats
        float* bufB = stageF + 5632;
        float* bufC = stageF + 6912;             // ends 8192 floats = 32768 B
        int bid = bid3 / 3;                      // 0..1023
        int m0 = bid * 128;
        if (t < 128) midx[t] = mask[m0 + t];
        __syncthreads();
        #pragma unroll
        for (int rr = rg; rr < 128; rr += 16) {
            int i = midx[rr];
            int bl = i >> 9, b = i >> 15, r = i & 511;
            const float* up = &U[bl * HID + c8];
            const float* vp = &V[(b * NR + r) * HID + c8];
            float4 u0 = *(const float4*)up, u1 = *(const float4*)(up + 4);
            float4 v0 = *(const float4*)vp, v1 = *(const float4*)(vp + 4);
            union { bf16x8 v; ushort u[8]; } o;
            o.u[0] = f2bf(elu1(fmaf(u0.x + v0.x, sc0.x, sh0.x)));
            o.u[1] = f2bf(elu1(fmaf(u0.y + v0.y, sc0.y, sh0.y)));
            o.u[2] = f2bf(elu1(fmaf(u0.z + v0.z, sc0.z, sh0.z)));
            o.u[3] = f2bf(elu1(fmaf(u0.w + v0.w, sc0.w, sh0.w)));
            o.u[4] = f2bf(elu1(fmaf(u1.x + v1.x, sc1.x, sh1.x)));
            o.u[5] = f2bf(elu1(fmaf(u1.y + v1.y, sc1.y, sh1.y)));
            o.u[6] = f2bf(elu1(fmaf(u1.z + v1.z, sc1.z, sh1.z)));
            o.u[7] = f2bf(elu1(fmaf(u1.w + v1.w, sc1.w, sh1.w)));
            *(bf16x8*)&hT[rr * LDH + c8] = o.v;
        }
        __syncthreads();
        int wrow = w * 32;
        f32x4 acc[2][2];
        #pragma unroll
        for (int mi = 0; mi < 2; mi++)
            #pragma unroll
            for (int ni = 0; ni < 2; ni++) acc[mi][ni] = (f32x4){0.f, 0.f, 0.f, 0.f};
        const bf16x8* wBv = (const bf16x8*)wBg;
        #pragma unroll
        for (int ks = 0; ks < 4; ks++) {
            int ko = ks * 32 + kgrp * 8;
            bf16x8 a0 = *(const bf16x8*)&hT[(wrow + lrow) * LDH + ko];
            bf16x8 a1 = *(const bf16x8*)&hT[(wrow + 16 + lrow) * LDH + ko];
            bf16x8 b0 = wBv[ks * 64 + lane];
            bf16x8 b1 = wBv[(4 + ks) * 64 + lane];
            acc[0][0] = __builtin_amdgcn_mfma_f32_16x16x32_bf16(a0, b0, acc[0][0], 0, 0, 0);
            acc[0][1] = __builtin_amdgcn_mfma_f32_16x16x32_bf16(a0, b1, acc[0][1], 0, 0, 0);
            acc[1][0] = __builtin_amdgcn_mfma_f32_16x16x32_bf16(a1, b0, acc[1][0], 0, 0, 0);
            acc[1][1] = __builtin_amdgcn_mfma_f32_16x16x32_bf16(a1, b1, acc[1][1], 0, 0, 0);
        }
        __syncthreads();   // all hT reads done before zl alias writes
        #pragma unroll
        for (int mi = 0; mi < 2; mi++)
            #pragma unroll
            for (int ni = 0; ni < 2; ni++)
                #pragma unroll
                for (int reg = 0; reg < 4; reg++) {
                    int row = wrow + mi * 16 + kgrp * 4 + reg;
                    zl[row * 33 + ni * 16 + lrow] = acc[mi][ni][reg];
                }
        __syncthreads();
        if (t < 128) {
            float zv[30];
            #pragma unroll
            for (int j = 0; j < 30; j++) zv[j] = zl[t * 33 + j];
            float lp[10], mx = -1e30f;
            #pragma unroll
            for (int j = 0; j < 10; j++) { lp[j] = zv[j] + bpi[j]; mx = fmaxf(mx, lp[j]); }
            float se = 0.f;
            #pragma unroll
            for (int j = 0; j < 10; j++) se += __expf(lp[j] - mx);
            float lse = mx + __logf(se);
            #pragma unroll
            for (int j = 0; j < 10; j++) lp[j] -= lse;
            float sg[10], muv[10];
            #pragma unroll
            for (int j = 0; j < 10; j++) sg[j] = elu1(zv[10 + j] + bsig[j]) + 1.1f;
            #pragma unroll
            for (int j = 0; j < 10; j++) muv[j] = elu1(zv[20 + j] + bmu[j]) + 1.0f;
            int i = midx[t];
            int bl = i >> 9, b = i >> 15, r = i & 511;
            float dx = posl[bl * 3]     - posr[(b * NR + r) * 3];
            float dy = posl[bl * 3 + 1] - posr[(b * NR + r) * 3 + 1];
            float dz = posl[bl * 3 + 2] - posr[(b * NR + r) * 3 + 2];
            float y = sqrtf(dx * dx + dy * dy + dz * dz);
            float tt[10], mm = -1e30f;
            #pragma unroll
            for (int j = 0; j < 10; j++) {
                float q = (y - muv[j]) / sg[j];
                float llv = -0.5f * q * q - __logf(sg[j]) - 0.91893853320467274f;
                tt[j] = lp[j] + llv; mm = fmaxf(mm, tt[j]);
            }
            float s2e = 0.f;
            #pragma unroll
            for (int j = 0; j < 10; j++) s2e += __expf(tt[j] - mm);
            float mdn = -(mm + __logf(s2e));
            #pragma unroll
            for (int j = 0; j < 10; j++) { bufA[t * 10 + j] = lp[j]; bufB[t * 10 + j] = sg[j]; bufC[t * 10 + j] = muv[j]; }
            mdnv[t] = mdn; mdnb[t] = b;
        }
        __syncthreads();
        {
            float4* oA = (float4*)&out_logpi[m0 * 10];
            float4* oB = (float4*)&out_sigma[m0 * 10];
            float4* oC = (float4*)&out_mu[m0 * 10];
            const float4* bA = (const float4*)bufA;
            const float4* bB = (const float4*)bufB;
            const float4* bC = (const float4*)bufC;
            #pragma unroll
            for (int i4 = t; i4 < 320; i4 += 256) { oA[i4] = bA[i4]; oB[i4] = bB[i4]; oC[i4] = bC[i4]; }
        }
        if (t < 64) {   // deterministic fixed-order partial sums: 8 chunks x 8 batches
            int bb = t & 7, chunk = t >> 3;
            float s = 0.f; int cnt = 0;
            for (int rr = chunk * 16; rr < chunk * 16 + 16; rr++)
                if (mdnb[rr] == bb) { s += mdnv[rr]; cnt++; }
            psLds[chunk][bb] = s; pcLds[chunk][bb] = (float)cnt;
        }
        __syncthreads();
        if (t < 8) {
            float s = 0.f, cnt = 0.f;
            #pragma unroll
            for (int chunk = 0; chunk < 8; chunk++) { s += psLds[chunk][t]; cnt += pcLds[chunk][t]; }
            mdn_psum[bid * 8 + t] = s; mdn_pcnt[bid * 8 + t] = cnt;
        }
    }
}

// ---------------- k7: prob = segment mean (1024 psum rows) ----------------
__global__ __launch_bounds__(256) void k7_prob(const float* __restrict__ psum, const float* __restrict__ pcnt,
        float* __restrict__ prob) {
    int b = blockIdx.x, t = threadIdx.x;
    float s = 0, c = 0;
    for (int idx = t; idx < 1024; idx += 256) { s += psum[idx * 8 + b]; c += pcnt[idx * 8 + b]; }
    __shared__ float rs[256], rc[256];
    rs[t] = s; rc[t] = c;
    __syncthreads();
    for (int off = 128; off > 0; off >>= 1) {
        if (t < off) { rs[t] += rs[t + off]; rc[t] += rc[t + off]; }
        __syncthreads();
    }
    if (t == 0) prob[b] = rs[0] / fmaxf(rc[0], 1.f);
}

extern "C" void kernel_launch(void* const* d_in, const int* in_sizes, int n_in,
                              void* d_out, int out_size, void* d_ws, size_t ws_size,
                              hipStream_t stream) {
    const float* flig  = (const float*)d_in[0];
    const float* posl  = (const float*)d_in[1];
    const float* frec  = (const float*)d_in[3];
    const float* posr  = (const float*)d_in[4];
    const int*   mask  = (const int*)d_in[6];
    const float* W1    = (const float*)d_in[7];
    const float* b1    = (const float*)d_in[8];
    const float* g1    = (const float*)d_in[9];
    const float* beta1 = (const float*)d_in[10];
    const float* Wpi   = (const float*)d_in[11];
    const float* bpi   = (const float*)d_in[12];
    const float* Wsig  = (const float*)d_in[13];
    const float* bsig  = (const float*)d_in[14];
    const float* Wmu   = (const float*)d_in[15];
    const float* bmu   = (const float*)d_in[16];
    const float* Wc1   = (const float*)d_in[17];
    const float* bc1   = (const float*)d_in[18];
    const float* gc    = (const float*)d_in[19];
    const float* betac = (const float*)d_in[20];
    const float* Wc2   = (const float*)d_in[21];
    const float* bc2   = (const float*)d_in[22];

    float* ws = (float*)d_ws;
    float* U      = ws;                 // 65536
    float* V      = ws + 65536;         // 524288 (end 589824)
    float* scale1 = ws + 589824;        // 128
    float* shift1 = ws + 589952;
    float* Af     = ws + 590080;
    float* Bf2    = ws + 590208;        // (end 590336)
    ushort* wB    = (ushort*)(ws + 590336);   // 16384 bf16 = 8192 f (end 598528)
    ushort* wBg   = (ushort*)(ws + 598528);   // 4096 bf16 = 2048 f (end 600576)
    float* bn2s   = ws + 600576;        // 256*128 = 32768 (end 633344)
    float* bn2s2  = ws + 633344;        // (end 666112)
    float* psum   = ws + 666112;        // 8192 (end 674304)
    float* pcnt   = ws + 674304;        // (end 682496)
    float* partS  = ws + 682496;        // 576*128 = 73728 (end 756224)
    float* partS2 = ws + 756224;        // (end 829952)

    float* out = (float*)d_out;
    float* out_logpi   = out;
    float* out_sigma   = out + 1310720;
    float* out_mu      = out + 2621440;
    float* out_prob    = out + 3932160;
    float* out_contact = out + 3932168;
    float* out_truth   = out + 4194312;

    k1_uv<<<dim3(704), dim3(128), 0, stream>>>(flig, frec, W1, b1, Wc1, Wpi, Wsig, Wmu,
        U, V, partS, partS2, wB, wBg);
    k2_bn1<<<dim3(1), dim3(1024), 0, stream>>>(partS, partS2, g1, beta1, scale1, shift1);
    k_stats<<<dim3(256), dim3(256), 0, stream>>>(U, V, scale1, shift1, wB, bc1, bn2s, bn2s2);
    k4_bn2<<<dim3(1), dim3(1024), 0, stream>>>(bn2s, bn2s2, gc, betac, bc1, Af, Bf2);
    k_mix<<<dim3(3072), dim3(256), 0, stream>>>(mask, U, V, scale1, shift1, wB, wBg,
        Af, Bf2, Wc2, bc2, bpi, bsig, bmu, posl, posr,
        out_contact, out_truth, out_logpi, out_sigma, out_mu, psum, pcnt);
    k7_prob<<<dim3(8), dim3(256), 0, stream>>>(psum, pcnt, out_prob);
}

// Round 17
// 82.272 us; speedup vs baseline: 1.3703x; 1.0145x over previous
//
#include <hip/hip_runtime.h>
#include <hip/hip_bf16.h>
#include <math.h>

#define B_ 8
#define NL 64
#define NR 512
#define FD 128
#define HID 128
#define KM 10
#define P_ 262144
#define NSAMP 32768
#define M_ 131072
#define LDH 136   // padded LDS row stride in bf16 elems (272B, breaks bank conflicts)

typedef short bf16x8 __attribute__((ext_vector_type(8)));
typedef float f32x4 __attribute__((ext_vector_type(4)));

static __device__ __forceinline__ ushort f2bf(float x) {
    __hip_bfloat16 h = __float2bfloat16(x);   // RNE; compiler lowers to v_cvt_pk_bf16_f32 pairs
    union { __hip_bfloat16 b; ushort u; } v; v.b = h;
    return v.u;
}
static __device__ __forceinline__ float elu1(float x) {
    return x > 0.f ? x : (__expf(x) - 1.f);
}

// ---------------- k1: U/V GEMM + col partials; blocks >=576 do weight pre-swizzle ----------------
__global__ __launch_bounds__(128) void k1_uv(const float* __restrict__ flig,
        const float* __restrict__ frec, const float* __restrict__ W1, const float* __restrict__ b1,
        const float* __restrict__ Wc1, const float* __restrict__ Wpi,
        const float* __restrict__ Wsig, const float* __restrict__ Wmu,
        float* __restrict__ U, float* __restrict__ V,
        float* __restrict__ partS, float* __restrict__ partS2,
        ushort* __restrict__ wB, ushort* __restrict__ wBg) {
    __shared__ float fr[8][128];
    int bid = blockIdx.x, c = threadIdx.x;
    if (bid >= 576) {   // weight pre-swizzle path (128 blocks x 128 threads = 16384)
        int idx = (bid - 576) * 128 + c;
        {
            int j = idx & 7, lane = (idx >> 3) & 63, ks = (idx >> 9) & 3, ni = idx >> 11;
            int lrow = lane & 15, kgrp = lane >> 4;
            int n = ni * 16 + lrow, k = ks * 32 + kgrp * 8 + j;
            wB[idx] = f2bf(Wc1[k * HID + n]);
        }
        if (idx < 4096) {
            int j = idx & 7, lane = (idx >> 3) & 63, ks = (idx >> 9) & 3, ni = (idx >> 11) & 1;
            int lrow = lane & 15, kgrp = lane >> 4;
            int n = ni * 16 + lrow, k = ks * 32 + kgrp * 8 + j;
            float wv = 0.f;
            if (n < 10) wv = Wpi[k * KM + n];
            else if (n < 20) wv = Wsig[k * KM + (n - 10)];
            else if (n < 30) wv = Wmu[k * KM + (n - 20)];
            wBg[idx] = f2bf(wv);
        }
        return;
    }
    const float* feat; const float* Wb; float* outp; float bias;
    if (bid < 64) {
        int rowbase = bid * 8;
        feat = flig + rowbase * FD; Wb = W1; outp = U + rowbase * HID; bias = b1[c];
    } else {
        int rowbase = (bid - 64) * 8;
        feat = frec + rowbase * FD; Wb = W1 + FD * HID; outp = V + rowbase * HID; bias = 0.f;
    }
    #pragma unroll
    for (int rr = 0; rr < 8; rr++) fr[rr][c] = feat[rr * FD + c];
    __syncthreads();
    float acc[8];
    #pragma unroll
    for (int rr = 0; rr < 8; rr++) acc[rr] = bias;
    #pragma unroll 4
    for (int k = 0; k < FD; k++) {
        float wv = Wb[k * HID + c];
        #pragma unroll
        for (int rr = 0; rr < 8; rr++) acc[rr] += fr[rr][k] * wv;
    }
    float su = 0.f, su2 = 0.f;
    #pragma unroll
    for (int rr = 0; rr < 8; rr++) {
        outp[rr * HID + c] = acc[rr];
        su += acc[rr]; su2 += acc[rr] * acc[rr];
    }
    partS[bid * 128 + c] = su;
    partS2[bid * 128 + c] = su2;
}

// ---------------- k2: fused BN1 stats reduce + finalize (grid 1 x 1024) ----------------
__global__ __launch_bounds__(1024) void k2_bn1(const float* __restrict__ partS, const float* __restrict__ partS2,
        const float* __restrict__ g1, const float* __restrict__ beta1,
        float* __restrict__ scale1, float* __restrict__ shift1) {
    __shared__ float sU[8][128], sU2[8][128], sV[8][128], sV2[8][128];
    int t = threadIdx.x, c = t & 127, b = t >> 7;
    float su = 0.f, su2 = 0.f;
    #pragma unroll
    for (int j = 0; j < 8; j++) { int row = b * 8 + j; su += partS[row * 128 + c]; su2 += partS2[row * 128 + c]; }
    float sv = 0.f, sv2 = 0.f;
    for (int j = 0; j < 64; j++) { int row = 64 + b * 64 + j; sv += partS[row * 128 + c]; sv2 += partS2[row * 128 + c]; }
    sU[b][c] = su; sU2[b][c] = su2; sV[b][c] = sv; sV2[b][c] = sv2;
    __syncthreads();
    if (t < 128) {
        float sum = 0.f, ssq = 0.f;
        #pragma unroll
        for (int bb = 0; bb < 8; bb++) {
            float s_ = sU[bb][t], v_ = sV[bb][t];
            sum += (float)NR * s_ + (float)NL * v_;
            ssq += (float)NR * sU2[bb][t] + 2.f * s_ * v_ + (float)NL * sV2[bb][t];
        }
        float inv = 1.f / (float)P_;
        float mean = sum * inv;
        float var = ssq * inv - mean * mean;
        float sc = g1[t] * rsqrtf(var + 1e-5f);
        scale1[t] = sc; shift1[t] = beta1[t] - mean * sc;
    }
}

// ---------------- k_stats: sampled BN2 stats (256 blocks x 1 tile-pair) ----------------
__global__ __launch_bounds__(256, 2) void k_stats(const float* __restrict__ U, const float* __restrict__ V,
        const float* __restrict__ scale1, const float* __restrict__ shift1,
        const ushort* __restrict__ wB, const float* __restrict__ bc1,
        float* __restrict__ bn2s, float* __restrict__ bn2s2) {
    __shared__ ushort hT[128 * LDH];
    int bid = blockIdx.x, t = threadIdx.x;
    int w = t >> 6, lane = t & 63, lrow = lane & 15, kgrp = lane >> 4;
    int c8 = (t & 15) * 8, rg = t >> 4;
    float4 sc0 = *(const float4*)&scale1[c8], sc1 = *(const float4*)&scale1[c8 + 4];
    float4 sh0 = *(const float4*)&shift1[c8], sh1 = *(const float4*)&shift1[c8 + 4];
    int bl0 = bid * 2, bl1 = bl0 + 1;
    const bf16x8* wBv = (const bf16x8*)wB;
    bf16x8 Bfr[2][4];
    #pragma unroll
    for (int nil = 0; nil < 2; nil++)
        #pragma unroll
        for (int ks = 0; ks < 4; ks++)
            Bfr[nil][ks] = wBv[((w * 2 + nil) * 4 + ks) * 64 + lane];
    float bc1v[2] = { bc1[w * 32 + lrow], bc1[w * 32 + 16 + lrow] };
    float4 uA0 = *(const float4*)&U[bl0 * HID + c8], uA1 = *(const float4*)&U[bl0 * HID + c8 + 4];
    float4 uB0 = *(const float4*)&U[bl1 * HID + c8], uB1 = *(const float4*)&U[bl1 * HID + c8 + 4];
    float4 ubA0, ubA1, ubB0, ubB1;
    ubA0.x = fmaf(uA0.x, sc0.x, sh0.x); ubA0.y = fmaf(uA0.y, sc0.y, sh0.y);
    ubA0.z = fmaf(uA0.z, sc0.z, sh0.z); ubA0.w = fmaf(uA0.w, sc0.w, sh0.w);
    ubA1.x = fmaf(uA1.x, sc1.x, sh1.x); ubA1.y = fmaf(uA1.y, sc1.y, sh1.y);
    ubA1.z = fmaf(uA1.z, sc1.z, sh1.z); ubA1.w = fmaf(uA1.w, sc1.w, sh1.w);
    ubB0.x = fmaf(uB0.x, sc0.x, sh0.x); ubB0.y = fmaf(uB0.y, sc0.y, sh0.y);
    ubB0.z = fmaf(uB0.z, sc0.z, sh0.z); ubB0.w = fmaf(uB0.w, sc0.w, sh0.w);
    ubB1.x = fmaf(uB1.x, sc1.x, sh1.x); ubB1.y = fmaf(uB1.y, sc1.y, sh1.y);
    ubB1.z = fmaf(uB1.z, sc1.z, sh1.z); ubB1.w = fmaf(uB1.w, sc1.w, sh1.w);
    int vbatch = (bl0 >> 6) << 9;
    #pragma unroll
    for (int k = 0; k < 8; k++) {
        int rr = rg + k * 16;
        int j = rr & 63;
        const float* vp = &V[(vbatch + j * 8) * HID + c8];
        float4 v0 = *(const float4*)vp, v1 = *(const float4*)(vp + 4);
        float4 ub0 = (k < 4) ? ubA0 : ubB0;
        float4 ub1 = (k < 4) ? ubA1 : ubB1;
        union { bf16x8 v; ushort u[8]; } o;
        o.u[0] = f2bf(elu1(fmaf(v0.x, sc0.x, ub0.x)));
        o.u[1] = f2bf(elu1(fmaf(v0.y, sc0.y, ub0.y)));
        o.u[2] = f2bf(elu1(fmaf(v0.z, sc0.z, ub0.z)));
        o.u[3] = f2bf(elu1(fmaf(v0.w, sc0.w, ub0.w)));
        o.u[4] = f2bf(elu1(fmaf(v1.x, sc1.x, ub1.x)));
        o.u[5] = f2bf(elu1(fmaf(v1.y, sc1.y, ub1.y)));
        o.u[6] = f2bf(elu1(fmaf(v1.z, sc1.z, ub1.z)));
        o.u[7] = f2bf(elu1(fmaf(v1.w, sc1.w, ub1.w)));
        *(bf16x8*)&hT[rr * LDH + c8] = o.v;
    }
    __syncthreads();
    f32x4 acc[8][2];
    #pragma unroll
    for (int m = 0; m < 8; m++) { acc[m][0] = (f32x4){0,0,0,0}; acc[m][1] = (f32x4){0,0,0,0}; }
    #pragma unroll
    for (int m = 0; m < 8; m++) {
        #pragma unroll
        for (int ks = 0; ks < 4; ks++) {
            bf16x8 a = *(const bf16x8*)&hT[(m * 16 + lrow) * LDH + ks * 32 + kgrp * 8];
            acc[m][0] = __builtin_amdgcn_mfma_f32_16x16x32_bf16(a, Bfr[0][ks], acc[m][0], 0, 0, 0);
            acc[m][1] = __builtin_amdgcn_mfma_f32_16x16x32_bf16(a, Bfr[1][ks], acc[m][1], 0, 0, 0);
        }
    }
    float s[2] = {0.f, 0.f}, s2[2] = {0.f, 0.f};
    #pragma unroll
    for (int nil = 0; nil < 2; nil++)
        #pragma unroll
        for (int reg = 0; reg < 4; reg++)
            #pragma unroll
            for (int m = 0; m < 8; m++) {
                float vv = acc[m][nil][reg] + bc1v[nil];
                s[nil] += vv; s2[nil] += vv * vv;
            }
    #pragma unroll
    for (int nil = 0; nil < 2; nil++) {
        s[nil] += __shfl_xor(s[nil], 16);  s[nil] += __shfl_xor(s[nil], 32);
        s2[nil] += __shfl_xor(s2[nil], 16); s2[nil] += __shfl_xor(s2[nil], 32);
    }
    if (lane < 16) {
        bn2s[bid * 128 + w * 32 + lane]       = s[0];
        bn2s[bid * 128 + w * 32 + 16 + lane]  = s[1];
        bn2s2[bid * 128 + w * 32 + lane]      = s2[0];
        bn2s2[bid * 128 + w * 32 + 16 + lane] = s2[1];
    }
}

// ---------------- k4: sampled-BN2 finalize (grid 1 x 1024) ----------------
__global__ __launch_bounds__(1024) void k4_bn2(const float* __restrict__ bn2s, const float* __restrict__ bn2s2,
        const float* __restrict__ gc, const float* __restrict__ betac, const float* __restrict__ bc1,
        float* __restrict__ Af, float* __restrict__ Bf2) {
    __shared__ float rs[8][128], rs2[8][128];
    int t = threadIdx.x, c = t & 127, g = t >> 7;
    float s = 0.f, s2 = 0.f;
    for (int j = 0; j < 32; j++) { int row = g * 32 + j; s += bn2s[row * 128 + c]; s2 += bn2s2[row * 128 + c]; }
    rs[g][c] = s; rs2[g][c] = s2;
    __syncthreads();
    if (t < 128) {
        float ss = 0.f, ss2 = 0.f;
        #pragma unroll
        for (int gg = 0; gg < 8; gg++) { ss += rs[gg][t]; ss2 += rs2[gg][t]; }
        float inv = 1.f / (float)NSAMP;
        float mean = ss * inv, var = ss2 * inv - mean * mean;
        float sc = gc[t] * rsqrtf(var + 1e-5f);
        Af[t] = sc;
        Bf2[t] = (bc1[t] - mean) * sc + betac[t];
    }
}

// ---------------- k_mix: 3072 blocks — pattern of 3: {2x contact tile, 1x MDN-128} ----------------
__global__ __launch_bounds__(256, 2) void k_mix(const int* __restrict__ mask,
        const float* __restrict__ U, const float* __restrict__ V,
        const float* __restrict__ scale1, const float* __restrict__ shift1,
        const ushort* __restrict__ wB, const ushort* __restrict__ wBg,
        const float* __restrict__ Af, const float* __restrict__ Bf2,
        const float* __restrict__ Wc2, const float* __restrict__ bc2,
        const float* __restrict__ bpi, const float* __restrict__ bsig, const float* __restrict__ bmu,
        const float* __restrict__ posl, const float* __restrict__ posr,
        float* __restrict__ outc, float* __restrict__ outt,
        float* __restrict__ out_logpi, float* __restrict__ out_sigma, float* __restrict__ out_mu,
        float* __restrict__ mdn_psum, float* __restrict__ mdn_pcnt) {
    __shared__ ushort hT[128 * LDH];     // 34816 B
    __shared__ float part[4][128];       // 2048 B
    __shared__ int midx[128];
    __shared__ float mdnv[128];
    __shared__ int mdnb[128];
    __shared__ float psLds[8][8], pcLds[8][8];   // total ~38.9 KB => 4 blocks/CU
    int t = threadIdx.x;
    int bid3 = blockIdx.x;
    int phase = bid3 % 3;
    int w = t >> 6, lane = t & 63, lrow = lane & 15, kgrp = lane >> 4;
    int c8 = (t & 15) * 8, rg = t >> 4;
    float4 sc0 = *(const float4*)&scale1[c8], sc1 = *(const float4*)&scale1[c8 + 4];
    float4 sh0 = *(const float4*)&shift1[c8], sh1 = *(const float4*)&shift1[c8 + 4];

    if (phase < 2) {
        // ================= contact tile path =================
        int k3 = (bid3 / 3) * 2 + phase;                 // 0..2047
        int bid = (k3 & 7) * 256 + (k3 >> 3);            // bijective XCD-chunk swizzle
        int bl = bid >> 2, it = bid & 3;
        const bf16x8* wBv = (const bf16x8*)wB;
        bf16x8 Bfr[2][4];
        #pragma unroll
        for (int nil = 0; nil < 2; nil++)
            #pragma unroll
            for (int ks = 0; ks < 4; ks++)
                Bfr[nil][ks] = wBv[((w * 2 + nil) * 4 + ks) * 64 + lane];
        float av[2], bv[2], wv[2];
        #pragma unroll
        for (int nil = 0; nil < 2; nil++) {
            int c = w * 32 + nil * 16 + lrow;
            av[nil] = Af[c]; bv[nil] = Bf2[c]; wv[nil] = Wc2[c];
        }
        float bc2v = bc2[0];
        float4 u0 = *(const float4*)&U[bl * HID + c8];
        float4 u1 = *(const float4*)&U[bl * HID + c8 + 4];
        float4 ub0, ub1;
        ub0.x = fmaf(u0.x, sc0.x, sh0.x); ub0.y = fmaf(u0.y, sc0.y, sh0.y);
        ub0.z = fmaf(u0.z, sc0.z, sh0.z); ub0.w = fmaf(u0.w, sc0.w, sh0.w);
        ub1.x = fmaf(u1.x, sc1.x, sh1.x); ub1.y = fmaf(u1.y, sc1.y, sh1.y);
        ub1.z = fmaf(u1.z, sc1.z, sh1.z); ub1.w = fmaf(u1.w, sc1.w, sh1.w);
        int vtile = ((bl >> 6) << 9) + it * 128;
        #pragma unroll
        for (int rr = rg; rr < 128; rr += 16) {
            const float* vp = &V[(vtile + rr) * HID + c8];
            float4 v0 = *(const float4*)vp, v1 = *(const float4*)(vp + 4);
            union { bf16x8 v; ushort u[8]; } o;
            o.u[0] = f2bf(elu1(fmaf(v0.x, sc0.x, ub0.x)));
            o.u[1] = f2bf(elu1(fmaf(v0.y, sc0.y, ub0.y)));
            o.u[2] = f2bf(elu1(fmaf(v0.z, sc0.z, ub0.z)));
            o.u[3] = f2bf(elu1(fmaf(v0.w, sc0.w, ub0.w)));
            o.u[4] = f2bf(elu1(fmaf(v1.x, sc1.x, ub1.x)));
            o.u[5] = f2bf(elu1(fmaf(v1.y, sc1.y, ub1.y)));
            o.u[6] = f2bf(elu1(fmaf(v1.z, sc1.z, ub1.z)));
            o.u[7] = f2bf(elu1(fmaf(v1.w, sc1.w, ub1.w)));
            *(bf16x8*)&hT[rr * LDH + c8] = o.v;
        }
        __syncthreads();
        f32x4 acc[8][2];
        #pragma unroll
        for (int m = 0; m < 8; m++) { acc[m][0] = (f32x4){0,0,0,0}; acc[m][1] = (f32x4){0,0,0,0}; }
        #pragma unroll
        for (int m = 0; m < 8; m++) {
            #pragma unroll
            for (int ks = 0; ks < 4; ks++) {
                bf16x8 a = *(const bf16x8*)&hT[(m * 16 + lrow) * LDH + ks * 32 + kgrp * 8];
                acc[m][0] = __builtin_amdgcn_mfma_f32_16x16x32_bf16(a, Bfr[0][ks], acc[m][0], 0, 0, 0);
                acc[m][1] = __builtin_amdgcn_mfma_f32_16x16x32_bf16(a, Bfr[1][ks], acc[m][1], 0, 0, 0);
            }
        }
        #pragma unroll
        for (int reg = 0; reg < 4; reg++) {
            float pr[8];
            #pragma unroll
            for (int m = 0; m < 8; m++) pr[m] = 0.f;
            #pragma unroll
            for (int nil = 0; nil < 2; nil++)
                #pragma unroll
                for (int m = 0; m < 8; m++) {
                    float x = fmaf(acc[m][nil][reg], av[nil], bv[nil]);
                    pr[m] += fmaxf(x, 0.f) * wv[nil];
                }
            #pragma unroll
            for (int m = 0; m < 8; m++) {
                pr[m] += __shfl_xor(pr[m], 1); pr[m] += __shfl_xor(pr[m], 2);
                pr[m] += __shfl_xor(pr[m], 4); pr[m] += __shfl_xor(pr[m], 8);
            }
            if (lrow == 0) {
                #pragma unroll
                for (int m = 0; m < 8; m++) part[w][m * 16 + kgrp * 4 + reg] = pr[m];
            }
        }
        __syncthreads();
        if (t < 128) {
            int row = bid * 128 + t;
            outc[row] = part[0][t] + part[1][t] + part[2][t] + part[3][t] + bc2v;
            int pbl = row >> 9, pb = row >> 15, pr_ = row & 511;
            float dx = posl[pbl * 3]     - posr[(pb * NR + pr_) * 3];
            float dy = posl[pbl * 3 + 1] - posr[(pb * NR + pr_) * 3 + 1];
            float dz = posl[pbl * 3 + 2] - posr[(pb * NR + pr_) * 3 + 2];
            float y = sqrtf(dx * dx + dy * dy + dz * dz);
            outt[row] = (y < 8.0f) ? 1.0f : 0.0f;
        }
    } else {
        // ================= MDN path (128 rows) =================
        float* stageF = (float*)hT;
        float* zl   = stageF;                    // 128*33 = 4224 floats
        float* bufA = stageF + 4352;             // 1280 floats
        float* bufB = stageF + 5632;
        float* bufC = stageF + 6912;             // ends 8192 floats = 32768 B
        int bid = bid3 / 3;                      // 0..1023
        int m0 = bid * 128;
        if (t < 128) midx[t] = mask[m0 + t];
        __syncthreads();
        #pragma unroll
        for (int rr = rg; rr < 128; rr += 16) {
            int i = midx[rr];
            int bl = i >> 9, b = i >> 15, r = i & 511;
            const float* up = &U[bl * HID + c8];
            const float* vp = &V[(b * NR + r) * HID + c8];
            float4 u0 = *(const float4*)up, u1 = *(const float4*)(up + 4);
            float4 v0 = *(const float4*)vp, v1 = *(const float4*)(vp + 4);
            union { bf16x8 v; ushort u[8]; } o;
            o.u[0] = f2bf(elu1(fmaf(u0.x + v0.x, sc0.x, sh0.x)));
            o.u[1] = f2bf(elu1(fmaf(u0.y + v0.y, sc0.y, sh0.y)));
            o.u[2] = f2bf(elu1(fmaf(u0.z + v0.z, sc0.z, sh0.z)));
            o.u[3] = f2bf(elu1(fmaf(u0.w + v0.w, sc0.w, sh0.w)));
            o.u[4] = f2bf(elu1(fmaf(u1.x + v1.x, sc1.x, sh1.x)));
            o.u[5] = f2bf(elu1(fmaf(u1.y + v1.y, sc1.y, sh1.y)));
            o.u[6] = f2bf(elu1(fmaf(u1.z + v1.z, sc1.z, sh1.z)));
            o.u[7] = f2bf(elu1(fmaf(u1.w + v1.w, sc1.w, sh1.w)));
            *(bf16x8*)&hT[rr * LDH + c8] = o.v;
        }
        __syncthreads();
        int wrow = w * 32;
        f32x4 acc[2][2];
        #pragma unroll
        for (int mi = 0; mi < 2; mi++)
            #pragma unroll
            for (int ni = 0; ni < 2; ni++) acc[mi][ni] = (f32x4){0.f, 0.f, 0.f, 0.f};
        const bf16x8* wBv = (const bf16x8*)wBg;
        #pragma unroll
        for (int ks = 0; ks < 4; ks++) {
            int ko = ks * 32 + kgrp * 8;
            bf16x8 a0 = *(const bf16x8*)&hT[(wrow + lrow) * LDH + ko];
            bf16x8 a1 = *(const bf16x8*)&hT[(wrow + 16 + lrow) * LDH + ko];
            bf16x8 b0 = wBv[ks * 64 + lane];
            bf16x8 b1 = wBv[(4 + ks) * 64 + lane];
            acc[0][0] = __builtin_amdgcn_mfma_f32_16x16x32_bf16(a0, b0, acc[0][0], 0, 0, 0);
            acc[0][1] = __builtin_amdgcn_mfma_f32_16x16x32_bf16(a0, b1, acc[0][1], 0, 0, 0);
            acc[1][0] = __builtin_amdgcn_mfma_f32_16x16x32_bf16(a1, b0, acc[1][0], 0, 0, 0);
            acc[1][1] = __builtin_amdgcn_mfma_f32_16x16x32_bf16(a1, b1, acc[1][1], 0, 0, 0);
        }
        __syncthreads();   // all hT reads done before zl alias writes
        #pragma unroll
        for (int mi = 0; mi < 2; mi++)
            #pragma unroll
            for (int ni = 0; ni < 2; ni++)
                #pragma unroll
                for (int reg = 0; reg < 4; reg++) {
                    int row = wrow + mi * 16 + kgrp * 4 + reg;
                    zl[row * 33 + ni * 16 + lrow] = acc[mi][ni][reg];
                }
        __syncthreads();
        if (t < 128) {
            float zv[30];
            #pragma unroll
            for (int j = 0; j < 30; j++) zv[j] = zl[t * 33 + j];
            float lp[10], mx = -1e30f;
            #pragma unroll
            for (int j = 0; j < 10; j++) { lp[j] = zv[j] + bpi[j]; mx = fmaxf(mx, lp[j]); }
            float se = 0.f;
            #pragma unroll
            for (int j = 0; j < 10; j++) se += __expf(lp[j] - mx);
            float lse = mx + __logf(se);
            #pragma unroll
            for (int j = 0; j < 10; j++) lp[j] -= lse;
            float sg[10], muv[10];
            #pragma unroll
            for (int j = 0; j < 10; j++) sg[j] = elu1(zv[10 + j] + bsig[j]) + 1.1f;
            #pragma unroll
            for (int j = 0; j < 10; j++) muv[j] = elu1(zv[20 + j] + bmu[j]) + 1.0f;
            int i = midx[t];
            int bl = i >> 9, b = i >> 15, r = i & 511;
            float dx = posl[bl * 3]     - posr[(b * NR + r) * 3];
            float dy = posl[bl * 3 + 1] - posr[(b * NR + r) * 3 + 1];
            float dz = posl[bl * 3 + 2] - posr[(b * NR + r) * 3 + 2];
            float y = sqrtf(dx * dx + dy * dy + dz * dz);
            float tt[10], mm = -1e30f;
            #pragma unroll
            for (int j = 0; j < 10; j++) {
                float q = (y - muv[j]) / sg[j];
                float llv = -0.5f * q * q - __logf(sg[j]) - 0.91893853320467274f;
                tt[j] = lp[j] + llv; mm = fmaxf(mm, tt[j]);
            }
            float s2e = 0.f;
            #pragma unroll
            for (int j = 0; j < 10; j++) s2e += __expf(tt[j] - mm);
            float mdn = -(mm + __logf(s2e));
            #pragma unroll
            for (int j = 0; j < 10; j++) { bufA[t * 10 + j] = lp[j]; bufB[t * 10 + j] = sg[j]; bufC[t * 10 + j] = muv[j]; }
            mdnv[t] = mdn; mdnb[t] = b;
        }
        __syncthreads();
        {
            float4* oA = (float4*)&out_logpi[m0 * 10];
            float4* oB = (float4*)&out_sigma[m0 * 10];
            float4* oC = (float4*)&out_mu[m0 * 10];
            const float4* bA = (const float4*)bufA;
            const float4* bB = (const float4*)bufB;
            const float4* bC = (const float4*)bufC;
            #pragma unroll
            for (int i4 = t; i4 < 320; i4 += 256) { oA[i4] = bA[i4]; oB[i4] = bB[i4]; oC[i4] = bC[i4]; }
        }
        if (t < 64) {   // deterministic fixed-order partial sums: 8 chunks x 8 batches
            int bb = t & 7, chunk = t >> 3;
            float s = 0.f; int cnt = 0;
            for (int rr = chunk * 16; rr < chunk * 16 + 16; rr++)
                if (mdnb[rr] == bb) { s += mdnv[rr]; cnt++; }
            psLds[chunk][bb] = s; pcLds[chunk][bb] = (float)cnt;
        }
        __syncthreads();
        if (t < 8) {
            float s = 0.f, cnt = 0.f;
            #pragma unroll
            for (int chunk = 0; chunk < 8; chunk++) { s += psLds[chunk][t]; cnt += pcLds[chunk][t]; }
            mdn_psum[bid * 8 + t] = s; mdn_pcnt[bid * 8 + t] = cnt;
        }
    }
}

// ---------------- k7: prob = segment mean (1024 psum rows) ----------------
__global__ __launch_bounds__(256) void k7_prob(const float* __restrict__ psum, const float* __restrict__ pcnt,
        float* __restrict__ prob) {
    int b = blockIdx.x, t = threadIdx.x;
    float s = 0, c = 0;
    for (int idx = t; idx < 1024; idx += 256) { s += psum[idx * 8 + b]; c += pcnt[idx * 8 + b]; }
    __shared__ float rs[256], rc[256];
    rs[t] = s; rc[t] = c;
    __syncthreads();
    for (int off = 128; off > 0; off >>= 1) {
        if (t < off) { rs[t] += rs[t + off]; rc[t] += rc[t + off]; }
        __syncthreads();
    }
    if (t == 0) prob[b] = rs[0] / fmaxf(rc[0], 1.f);
}

extern "C" void kernel_launch(void* const* d_in, const int* in_sizes, int n_in,
                              void* d_out, int out_size, void* d_ws, size_t ws_size,
                              hipStream_t stream) {
    const float* flig  = (const float*)d_in[0];
    const float* posl  = (const float*)d_in[1];
    const float* frec  = (const float*)d_in[3];
    const float* posr  = (const float*)d_in[4];
    const int*   mask  = (const int*)d_in[6];
    const float* W1    = (const float*)d_in[7];
    const float* b1    = (const float*)d_in[8];
    const float* g1    = (const float*)d_in[9];
    const float* beta1 = (const float*)d_in[10];
    const float* Wpi   = (const float*)d_in[11];
    const float* bpi   = (const float*)d_in[12];
    const float* Wsig  = (const float*)d_in[13];
    const float* bsig  = (const float*)d_in[14];
    const float* Wmu   = (const float*)d_in[15];
    const float* bmu   = (const float*)d_in[16];
    const float* Wc1   = (const float*)d_in[17];
    const float* bc1   = (const float*)d_in[18];
    const float* gc    = (const float*)d_in[19];
    const float* betac = (const float*)d_in[20];
    const float* Wc2   = (const float*)d_in[21];
    const float* bc2   = (const float*)d_in[22];

    float* ws = (float*)d_ws;
    float* U      = ws;                 // 65536
    float* V      = ws + 65536;         // 524288 (end 589824)
    float* scale1 = ws + 589824;        // 128
    float* shift1 = ws + 589952;
    float* Af     = ws + 590080;
    float* Bf2    = ws + 590208;        // (end 590336)
    ushort* wB    = (ushort*)(ws + 590336);   // 16384 bf16 = 8192 f (end 598528)
    ushort* wBg   = (ushort*)(ws + 598528);   // 4096 bf16 = 2048 f (end 600576)
    float* bn2s   = ws + 600576;        // 256*128 = 32768 (end 633344)
    float* bn2s2  = ws + 633344;        // (end 666112)
    float* psum   = ws + 666112;        // 8192 (end 674304)
    float* pcnt   = ws + 674304;        // (end 682496)
    float* partS  = ws + 682496;        // 576*128 = 73728 (end 756224)
    float* partS2 = ws + 756224;        // (end 829952)

    float* out = (float*)d_out;
    float* out_logpi   = out;
    float* out_sigma   = out + 1310720;
    float* out_mu      = out + 2621440;
    float* out_prob    = out + 3932160;
    float* out_contact = out + 3932168;
    float* out_truth   = out + 4194312;

    k1_uv<<<dim3(704), dim3(128), 0, stream>>>(flig, frec, W1, b1, Wc1, Wpi, Wsig, Wmu,
        U, V, partS, partS2, wB, wBg);
    k2_bn1<<<dim3(1), dim3(1024), 0, stream>>>(partS, partS2, g1, beta1, scale1, shift1);
    k_stats<<<dim3(256), dim3(256), 0, stream>>>(U, V, scale1, shift1, wB, bc1, bn2s, bn2s2);
    k4_bn2<<<dim3(1), dim3(1024), 0, stream>>>(bn2s, bn2s2, gc, betac, bc1, Af, Bf2);
    k_mix<<<dim3(3072), dim3(256), 0, stream>>>(mask, U, V, scale1, shift1, wB, wBg,
        Af, Bf2, Wc2, bc2, bpi, bsig, bmu, posl, posr,
        out_contact, out_truth, out_logpi, out_sigma, out_mu, psum, pcnt);
    k7_prob<<<dim3(8), dim3(256), 0, stream>>>(psum, pcnt, out_prob);
}

// Round 18
// 80.833 us; speedup vs baseline: 1.3947x; 1.0178x over previous
//
#include <hip/hip_runtime.h>
#include <hip/hip_bf16.h>
#include <math.h>

#define B_ 8
#define NL 64
#define NR 512
#define FD 128
#define HID 128
#define KM 10
#define P_ 262144
#define NSAMP 32768
#define M_ 131072
#define LDH 136   // padded LDS row stride in bf16 elems (272B, breaks bank conflicts)

typedef short bf16x8 __attribute__((ext_vector_type(8)));
typedef float f32x4 __attribute__((ext_vector_type(4)));

static __device__ __forceinline__ ushort f2bf(float x) {
    __hip_bfloat16 h = __float2bfloat16(x);   // RNE; compiler lowers to v_cvt_pk_bf16_f32 pairs
    union { __hip_bfloat16 b; ushort u; } v; v.b = h;
    return v.u;
}
static __device__ __forceinline__ float elu1(float x) {
    return x > 0.f ? x : (__expf(x) - 1.f);
}

// ---------------- k1: U/V GEMM + col partials; blocks >=576 do weight pre-swizzle ----------------
__global__ __launch_bounds__(128) void k1_uv(const float* __restrict__ flig,
        const float* __restrict__ frec, const float* __restrict__ W1, const float* __restrict__ b1,
        const float* __restrict__ Wc1, const float* __restrict__ Wpi,
        const float* __restrict__ Wsig, const float* __restrict__ Wmu,
        float* __restrict__ U, float* __restrict__ V,
        float* __restrict__ partS, float* __restrict__ partS2,
        ushort* __restrict__ wB, ushort* __restrict__ wBg) {
    __shared__ float fr[8][128];
    int bid = blockIdx.x, c = threadIdx.x;
    if (bid >= 576) {   // weight pre-swizzle path (128 blocks x 128 threads = 16384)
        int idx = (bid - 576) * 128 + c;
        {
            int j = idx & 7, lane = (idx >> 3) & 63, ks = (idx >> 9) & 3, ni = idx >> 11;
            int lrow = lane & 15, kgrp = lane >> 4;
            int n = ni * 16 + lrow, k = ks * 32 + kgrp * 8 + j;
            wB[idx] = f2bf(Wc1[k * HID + n]);
        }
        if (idx < 4096) {
            int j = idx & 7, lane = (idx >> 3) & 63, ks = (idx >> 9) & 3, ni = (idx >> 11) & 1;
            int lrow = lane & 15, kgrp = lane >> 4;
            int n = ni * 16 + lrow, k = ks * 32 + kgrp * 8 + j;
            float wv = 0.f;
            if (n < 10) wv = Wpi[k * KM + n];
            else if (n < 20) wv = Wsig[k * KM + (n - 10)];
            else if (n < 30) wv = Wmu[k * KM + (n - 20)];
            wBg[idx] = f2bf(wv);
        }
        return;
    }
    const float* feat; const float* Wb; float* outp; float bias;
    if (bid < 64) {
        int rowbase = bid * 8;
        feat = flig + rowbase * FD; Wb = W1; outp = U + rowbase * HID; bias = b1[c];
    } else {
        int rowbase = (bid - 64) * 8;
        feat = frec + rowbase * FD; Wb = W1 + FD * HID; outp = V + rowbase * HID; bias = 0.f;
    }
    #pragma unroll
    for (int rr = 0; rr < 8; rr++) fr[rr][c] = feat[rr * FD + c];
    __syncthreads();
    float acc[8];
    #pragma unroll
    for (int rr = 0; rr < 8; rr++) acc[rr] = bias;
    #pragma unroll 4
    for (int k = 0; k < FD; k++) {
        float wv = Wb[k * HID + c];
        #pragma unroll
        for (int rr = 0; rr < 8; rr++) acc[rr] += fr[rr][k] * wv;
    }
    float su = 0.f, su2 = 0.f;
    #pragma unroll
    for (int rr = 0; rr < 8; rr++) {
        outp[rr * HID + c] = acc[rr];
        su += acc[rr]; su2 += acc[rr] * acc[rr];
    }
    partS[bid * 128 + c] = su;
    partS2[bid * 128 + c] = su2;
}

// ---------------- k2: fused BN1 stats reduce + finalize (grid 1 x 1024) ----------------
__global__ __launch_bounds__(1024) void k2_bn1(const float* __restrict__ partS, const float* __restrict__ partS2,
        const float* __restrict__ g1, const float* __restrict__ beta1,
        float* __restrict__ scale1, float* __restrict__ shift1) {
    __shared__ float sU[8][128], sU2[8][128], sV[8][128], sV2[8][128];
    int t = threadIdx.x, c = t & 127, b = t >> 7;
    float su = 0.f, su2 = 0.f;
    #pragma unroll
    for (int j = 0; j < 8; j++) { int row = b * 8 + j; su += partS[row * 128 + c]; su2 += partS2[row * 128 + c]; }
    float sv = 0.f, sv2 = 0.f;
    for (int j = 0; j < 64; j++) { int row = 64 + b * 64 + j; sv += partS[row * 128 + c]; sv2 += partS2[row * 128 + c]; }
    sU[b][c] = su; sU2[b][c] = su2; sV[b][c] = sv; sV2[b][c] = sv2;
    __syncthreads();
    if (t < 128) {
        float sum = 0.f, ssq = 0.f;
        #pragma unroll
        for (int bb = 0; bb < 8; bb++) {
            float s_ = sU[bb][t], v_ = sV[bb][t];
            sum += (float)NR * s_ + (float)NL * v_;
            ssq += (float)NR * sU2[bb][t] + 2.f * s_ * v_ + (float)NL * sV2[bb][t];
        }
        float inv = 1.f / (float)P_;
        float mean = sum * inv;
        float var = ssq * inv - mean * mean;
        float sc = g1[t] * rsqrtf(var + 1e-5f);
        scale1[t] = sc; shift1[t] = beta1[t] - mean * sc;
    }
}

// ---------------- k_stats: sampled BN2 stats (256 blocks x 1 tile-pair) ----------------
__global__ __launch_bounds__(256, 2) void k_stats(const float* __restrict__ U, const float* __restrict__ V,
        const float* __restrict__ scale1, const float* __restrict__ shift1,
        const ushort* __restrict__ wB, const float* __restrict__ bc1,
        float* __restrict__ bn2s, float* __restrict__ bn2s2) {
    __shared__ ushort hT[128 * LDH];
    int bid = blockIdx.x, t = threadIdx.x;
    int w = t >> 6, lane = t & 63, lrow = lane & 15, kgrp = lane >> 4;
    int c8 = (t & 15) * 8, rg = t >> 4;
    float4 sc0 = *(const float4*)&scale1[c8], sc1 = *(const float4*)&scale1[c8 + 4];
    float4 sh0 = *(const float4*)&shift1[c8], sh1 = *(const float4*)&shift1[c8 + 4];
    int bl0 = bid * 2, bl1 = bl0 + 1;
    const bf16x8* wBv = (const bf16x8*)wB;
    bf16x8 Bfr[2][4];
    #pragma unroll
    for (int nil = 0; nil < 2; nil++)
        #pragma unroll
        for (int ks = 0; ks < 4; ks++)
            Bfr[nil][ks] = wBv[((w * 2 + nil) * 4 + ks) * 64 + lane];
    float bc1v[2] = { bc1[w * 32 + lrow], bc1[w * 32 + 16 + lrow] };
    float4 uA0 = *(const float4*)&U[bl0 * HID + c8], uA1 = *(const float4*)&U[bl0 * HID + c8 + 4];
    float4 uB0 = *(const float4*)&U[bl1 * HID + c8], uB1 = *(const float4*)&U[bl1 * HID + c8 + 4];
    float4 ubA0, ubA1, ubB0, ubB1;
    ubA0.x = fmaf(uA0.x, sc0.x, sh0.x); ubA0.y = fmaf(uA0.y, sc0.y, sh0.y);
    ubA0.z = fmaf(uA0.z, sc0.z, sh0.z); ubA0.w = fmaf(uA0.w, sc0.w, sh0.w);
    ubA1.x = fmaf(uA1.x, sc1.x, sh1.x); ubA1.y = fmaf(uA1.y, sc1.y, sh1.y);
    ubA1.z = fmaf(uA1.z, sc1.z, sh1.z); ubA1.w = fmaf(uA1.w, sc1.w, sh1.w);
    ubB0.x = fmaf(uB0.x, sc0.x, sh0.x); ubB0.y = fmaf(uB0.y, sc0.y, sh0.y);
    ubB0.z = fmaf(uB0.z, sc0.z, sh0.z); ubB0.w = fmaf(uB0.w, sc0.w, sh0.w);
    ubB1.x = fmaf(uB1.x, sc1.x, sh1.x); ubB1.y = fmaf(uB1.y, sc1.y, sh1.y);
    ubB1.z = fmaf(uB1.z, sc1.z, sh1.z); ubB1.w = fmaf(uB1.w, sc1.w, sh1.w);
    int vbatch = (bl0 >> 6) << 9;
    #pragma unroll
    for (int k = 0; k < 8; k++) {
        int rr = rg + k * 16;
        int j = rr & 63;
        const float* vp = &V[(vbatch + j * 8) * HID + c8];
        float4 v0 = *(const float4*)vp, v1 = *(const float4*)(vp + 4);
        float4 ub0 = (k < 4) ? ubA0 : ubB0;
        float4 ub1 = (k < 4) ? ubA1 : ubB1;
        union { bf16x8 v; ushort u[8]; } o;
        o.u[0] = f2bf(elu1(fmaf(v0.x, sc0.x, ub0.x)));
        o.u[1] = f2bf(elu1(fmaf(v0.y, sc0.y, ub0.y)));
        o.u[2] = f2bf(elu1(fmaf(v0.z, sc0.z, ub0.z)));
        o.u[3] = f2bf(elu1(fmaf(v0.w, sc0.w, ub0.w)));
        o.u[4] = f2bf(elu1(fmaf(v1.x, sc1.x, ub1.x)));
        o.u[5] = f2bf(elu1(fmaf(v1.y, sc1.y, ub1.y)));
        o.u[6] = f2bf(elu1(fmaf(v1.z, sc1.z, ub1.z)));
        o.u[7] = f2bf(elu1(fmaf(v1.w, sc1.w, ub1.w)));
        *(bf16x8*)&hT[rr * LDH + c8] = o.v;
    }
    __syncthreads();
    f32x4 acc[8][2];
    #pragma unroll
    for (int m = 0; m < 8; m++) { acc[m][0] = (f32x4){0,0,0,0}; acc[m][1] = (f32x4){0,0,0,0}; }
    #pragma unroll
    for (int m = 0; m < 8; m++) {
        #pragma unroll
        for (int ks = 0; ks < 4; ks++) {
            bf16x8 a = *(const bf16x8*)&hT[(m * 16 + lrow) * LDH + ks * 32 + kgrp * 8];
            acc[m][0] = __builtin_amdgcn_mfma_f32_16x16x32_bf16(a, Bfr[0][ks], acc[m][0], 0, 0, 0);
            acc[m][1] = __builtin_amdgcn_mfma_f32_16x16x32_bf16(a, Bfr[1][ks], acc[m][1], 0, 0, 0);
        }
    }
    float s[2] = {0.f, 0.f}, s2[2] = {0.f, 0.f};
    #pragma unroll
    for (int nil = 0; nil < 2; nil++)
        #pragma unroll
        for (int reg = 0; reg < 4; reg++)
            #pragma unroll
            for (int m = 0; m < 8; m++) {
                float vv = acc[m][nil][reg] + bc1v[nil];
                s[nil] += vv; s2[nil] += vv * vv;
            }
    #pragma unroll
    for (int nil = 0; nil < 2; nil++) {
        s[nil] += __shfl_xor(s[nil], 16);  s[nil] += __shfl_xor(s[nil], 32);
        s2[nil] += __shfl_xor(s2[nil], 16); s2[nil] += __shfl_xor(s2[nil], 32);
    }
    if (lane < 16) {
        bn2s[bid * 128 + w * 32 + lane]       = s[0];
        bn2s[bid * 128 + w * 32 + 16 + lane]  = s[1];
        bn2s2[bid * 128 + w * 32 + lane]      = s2[0];
        bn2s2[bid * 128 + w * 32 + 16 + lane] = s2[1];
    }
}

// ---------------- k4: sampled-BN2 finalize (grid 1 x 1024) ----------------
__global__ __launch_bounds__(1024) void k4_bn2(const float* __restrict__ bn2s, const float* __restrict__ bn2s2,
        const float* __restrict__ gc, const float* __restrict__ betac, const float* __restrict__ bc1,
        float* __restrict__ Af, float* __restrict__ Bf2) {
    __shared__ float rs[8][128], rs2[8][128];
    int t = threadIdx.x, c = t & 127, g = t >> 7;
    float s = 0.f, s2 = 0.f;
    for (int j = 0; j < 32; j++) { int row = g * 32 + j; s += bn2s[row * 128 + c]; s2 += bn2s2[row * 128 + c]; }
    rs[g][c] = s; rs2[g][c] = s2;
    __syncthreads();
    if (t < 128) {
        float ss = 0.f, ss2 = 0.f;
        #pragma unroll
        for (int gg = 0; gg < 8; gg++) { ss += rs[gg][t]; ss2 += rs2[gg][t]; }
        float inv = 1.f / (float)NSAMP;
        float mean = ss * inv, var = ss2 * inv - mean * mean;
        float sc = gc[t] * rsqrtf(var + 1e-5f);
        Af[t] = sc;
        Bf2[t] = (bc1[t] - mean) * sc + betac[t];
    }
}

// ---------------- k_mix: 3072 blocks — pattern of 3: {2x contact tile, 1x MDN-128} ----------------
__global__ __launch_bounds__(256, 2) void k_mix(const int* __restrict__ mask,
        const float* __restrict__ U, const float* __restrict__ V,
        const float* __restrict__ scale1, const float* __restrict__ shift1,
        const ushort* __restrict__ wB, const ushort* __restrict__ wBg,
        const float* __restrict__ Af, const float* __restrict__ Bf2,
        const float* __restrict__ Wc2, const float* __restrict__ bc2,
        const float* __restrict__ bpi, const float* __restrict__ bsig, const float* __restrict__ bmu,
        const float* __restrict__ posl, const float* __restrict__ posr,
        float* __restrict__ outc, float* __restrict__ outt,
        float* __restrict__ out_logpi, float* __restrict__ out_sigma, float* __restrict__ out_mu,
        float* __restrict__ mdn_psum, float* __restrict__ mdn_pcnt) {
    __shared__ ushort hT[128 * LDH];     // 34816 B (also aliased as [128][68] float scratch)
    __shared__ int midx[128];
    __shared__ float mdnv[128];
    __shared__ int mdnb[128];
    __shared__ float psLds[8][8], pcLds[8][8];   // total ~36.9 KB => 4 blocks/CU
    int t = threadIdx.x;
    int bid3 = blockIdx.x;
    int phase = bid3 % 3;
    int w = t >> 6, lane = t & 63, lrow = lane & 15, kgrp = lane >> 4;
    int c8 = (t & 15) * 8, rg = t >> 4;
    float4 sc0 = *(const float4*)&scale1[c8], sc1 = *(const float4*)&scale1[c8 + 4];
    float4 sh0 = *(const float4*)&shift1[c8], sh1 = *(const float4*)&shift1[c8 + 4];

    if (phase < 2) {
        // ================= contact tile path =================
        int k3 = (bid3 / 3) * 2 + phase;                 // 0..2047
        int bid = (k3 & 7) * 256 + (k3 >> 3);            // bijective XCD-chunk swizzle
        int bl = bid >> 2, it = bid & 3;
        const bf16x8* wBv = (const bf16x8*)wB;
        bf16x8 Bfr[2][4];
        #pragma unroll
        for (int nil = 0; nil < 2; nil++)
            #pragma unroll
            for (int ks = 0; ks < 4; ks++)
                Bfr[nil][ks] = wBv[((w * 2 + nil) * 4 + ks) * 64 + lane];
        float av[2], bv[2], wv[2];
        #pragma unroll
        for (int nil = 0; nil < 2; nil++) {
            int c = w * 32 + nil * 16 + lrow;
            av[nil] = Af[c]; bv[nil] = Bf2[c]; wv[nil] = Wc2[c];
        }
        float bc2v = bc2[0];
        float4 u0 = *(const float4*)&U[bl * HID + c8];
        float4 u1 = *(const float4*)&U[bl * HID + c8 + 4];
        float4 ub0, ub1;
        ub0.x = fmaf(u0.x, sc0.x, sh0.x); ub0.y = fmaf(u0.y, sc0.y, sh0.y);
        ub0.z = fmaf(u0.z, sc0.z, sh0.z); ub0.w = fmaf(u0.w, sc0.w, sh0.w);
        ub1.x = fmaf(u1.x, sc1.x, sh1.x); ub1.y = fmaf(u1.y, sc1.y, sh1.y);
        ub1.z = fmaf(u1.z, sc1.z, sh1.z); ub1.w = fmaf(u1.w, sc1.w, sh1.w);
        int vtile = ((bl >> 6) << 9) + it * 128;
        #pragma unroll
        for (int rr = rg; rr < 128; rr += 16) {
            const float* vp = &V[(vtile + rr) * HID + c8];
            float4 v0 = *(const float4*)vp, v1 = *(const float4*)(vp + 4);
            union { bf16x8 v; ushort u[8]; } o;
            o.u[0] = f2bf(elu1(fmaf(v0.x, sc0.x, ub0.x)));
            o.u[1] = f2bf(elu1(fmaf(v0.y, sc0.y, ub0.y)));
            o.u[2] = f2bf(elu1(fmaf(v0.z, sc0.z, ub0.z)));
            o.u[3] = f2bf(elu1(fmaf(v0.w, sc0.w, ub0.w)));
            o.u[4] = f2bf(elu1(fmaf(v1.x, sc1.x, ub1.x)));
            o.u[5] = f2bf(elu1(fmaf(v1.y, sc1.y, ub1.y)));
            o.u[6] = f2bf(elu1(fmaf(v1.z, sc1.z, ub1.z)));
            o.u[7] = f2bf(elu1(fmaf(v1.w, sc1.w, ub1.w)));
            *(bf16x8*)&hT[rr * LDH + c8] = o.v;
        }
        __syncthreads();
        f32x4 acc[8][2];
        #pragma unroll
        for (int m = 0; m < 8; m++) { acc[m][0] = (f32x4){0,0,0,0}; acc[m][1] = (f32x4){0,0,0,0}; }
        #pragma unroll
        for (int m = 0; m < 8; m++) {
            #pragma unroll
            for (int ks = 0; ks < 4; ks++) {
                bf16x8 a = *(const bf16x8*)&hT[(m * 16 + lrow) * LDH + ks * 32 + kgrp * 8];
                acc[m][0] = __builtin_amdgcn_mfma_f32_16x16x32_bf16(a, Bfr[0][ks], acc[m][0], 0, 0, 0);
                acc[m][1] = __builtin_amdgcn_mfma_f32_16x16x32_bf16(a, Bfr[1][ks], acc[m][1], 0, 0, 0);
            }
        }
        __syncthreads();   // all hT reads complete before alias overwrite
        // epilogue: nil-merge in registers, LDS transpose-reduce (no shuffles)
        float* scrF = (float*)hT;   // [128][68] floats = 34816 B
        #pragma unroll
        for (int m = 0; m < 8; m++) {
            #pragma unroll
            for (int reg = 0; reg < 4; reg++) {
                float y0 = fmaf(acc[m][0][reg], av[0], bv[0]);
                float y1 = fmaf(acc[m][1][reg], av[1], bv[1]);
                float pr = fmaxf(y0, 0.f) * wv[0] + fmaxf(y1, 0.f) * wv[1];
                int row = m * 16 + kgrp * 4 + reg;
                scrF[row * 68 + w * 16 + lrow] = pr;
            }
        }
        __syncthreads();
        if (t < 128) {
            const float4* rp = (const float4*)&scrF[t * 68];
            float s = 0.f;
            #pragma unroll
            for (int q = 0; q < 16; q++) {
                float4 v = rp[q];
                s += v.x + v.y + v.z + v.w;
            }
            int row = bid * 128 + t;
            outc[row] = s + bc2v;
            int pbl = row >> 9, pb = row >> 15, pr_ = row & 511;
            float dx = posl[pbl * 3]     - posr[(pb * NR + pr_) * 3];
            float dy = posl[pbl * 3 + 1] - posr[(pb * NR + pr_) * 3 + 1];
            float dz = posl[pbl * 3 + 2] - posr[(pb * NR + pr_) * 3 + 2];
            float y = sqrtf(dx * dx + dy * dy + dz * dz);
            outt[row] = (y < 8.0f) ? 1.0f : 0.0f;
        }
    } else {
        // ================= MDN path (128 rows) =================
        float* stageF = (float*)hT;
        float* zl   = stageF;                    // 128*33 = 4224 floats
        float* bufA = stageF + 4352;             // 1280 floats
        float* bufB = stageF + 5632;
        float* bufC = stageF + 6912;             // ends 8192 floats = 32768 B
        int bid = bid3 / 3;                      // 0..1023
        int m0 = bid * 128;
        if (t < 128) midx[t] = mask[m0 + t];
        __syncthreads();
        #pragma unroll
        for (int rr = rg; rr < 128; rr += 16) {
            int i = midx[rr];
            int bl = i >> 9, b = i >> 15, r = i & 511;
            const float* up = &U[bl * HID + c8];
            const float* vp = &V[(b * NR + r) * HID + c8];
            float4 u0 = *(const float4*)up, u1 = *(const float4*)(up + 4);
            float4 v0 = *(const float4*)vp, v1 = *(const float4*)(vp + 4);
            union { bf16x8 v; ushort u[8]; } o;
            o.u[0] = f2bf(elu1(fmaf(u0.x + v0.x, sc0.x, sh0.x)));
            o.u[1] = f2bf(elu1(fmaf(u0.y + v0.y, sc0.y, sh0.y)));
            o.u[2] = f2bf(elu1(fmaf(u0.z + v0.z, sc0.z, sh0.z)));
            o.u[3] = f2bf(elu1(fmaf(u0.w + v0.w, sc0.w, sh0.w)));
            o.u[4] = f2bf(elu1(fmaf(u1.x + v1.x, sc1.x, sh1.x)));
            o.u[5] = f2bf(elu1(fmaf(u1.y + v1.y, sc1.y, sh1.y)));
            o.u[6] = f2bf(elu1(fmaf(u1.z + v1.z, sc1.z, sh1.z)));
            o.u[7] = f2bf(elu1(fmaf(u1.w + v1.w, sc1.w, sh1.w)));
            *(bf16x8*)&hT[rr * LDH + c8] = o.v;
        }
        __syncthreads();
        int wrow = w * 32;
        f32x4 acc[2][2];
        #pragma unroll
        for (int mi = 0; mi < 2; mi++)
            #pragma unroll
            for (int ni = 0; ni < 2; ni++) acc[mi][ni] = (f32x4){0.f, 0.f, 0.f, 0.f};
        const bf16x8* wBv = (const bf16x8*)wBg;
        #pragma unroll
        for (int ks = 0; ks < 4; ks++) {
            int ko = ks * 32 + kgrp * 8;
            bf16x8 a0 = *(const bf16x8*)&hT[(wrow + lrow) * LDH + ko];
            bf16x8 a1 = *(const bf16x8*)&hT[(wrow + 16 + lrow) * LDH + ko];
            bf16x8 b0 = wBv[ks * 64 + lane];
            bf16x8 b1 = wBv[(4 + ks) * 64 + lane];
            acc[0][0] = __builtin_amdgcn_mfma_f32_16x16x32_bf16(a0, b0, acc[0][0], 0, 0, 0);
            acc[0][1] = __builtin_amdgcn_mfma_f32_16x16x32_bf16(a0, b1, acc[0][1], 0, 0, 0);
            acc[1][0] = __builtin_amdgcn_mfma_f32_16x16x32_bf16(a1, b0, acc[1][0], 0, 0, 0);
            acc[1][1] = __builtin_amdgcn_mfma_f32_16x16x32_bf16(a1, b1, acc[1][1], 0, 0, 0);
        }
        __syncthreads();   // all hT reads done before zl alias writes
        #pragma unroll
        for (int mi = 0; mi < 2; mi++)
            #pragma unroll
            for (int ni = 0; ni < 2; ni++)
                #pragma unroll
                for (int reg = 0; reg < 4; reg++) {
                    int row = wrow + mi * 16 + kgrp * 4 + reg;
                    zl[row * 33 + ni * 16 + lrow] = acc[mi][ni][reg];
                }
        __syncthreads();
        if (t < 128) {
            float zv[30];
            #pragma unroll
            for (int j = 0; j < 30; j++) zv[j] = zl[t * 33 + j];
            float lp[10], mx = -1e30f;
            #pragma unroll
            for (int j = 0; j < 10; j++) { lp[j] = zv[j] + bpi[j]; mx = fmaxf(mx, lp[j]); }
            float se = 0.f;
            #pragma unroll
            for (int j = 0; j < 10; j++) se += __expf(lp[j] - mx);
            float lse = mx + __logf(se);
            #pragma unroll
            for (int j = 0; j < 10; j++) lp[j] -= lse;
            float sg[10], muv[10];
            #pragma unroll
            for (int j = 0; j < 10; j++) sg[j] = elu1(zv[10 + j] + bsig[j]) + 1.1f;
            #pragma unroll
            for (int j = 0; j < 10; j++) muv[j] = elu1(zv[20 + j] + bmu[j]) + 1.0f;
            int i = midx[t];
            int bl = i >> 9, b = i >> 15, r = i & 511;
            float dx = posl[bl * 3]     - posr[(b * NR + r) * 3];
            float dy = posl[bl * 3 + 1] - posr[(b * NR + r) * 3 + 1];
            float dz = posl[bl * 3 + 2] - posr[(b * NR + r) * 3 + 2];
            float y = sqrtf(dx * dx + dy * dy + dz * dz);
            float tt[10], mm = -1e30f;
            #pragma unroll
            for (int j = 0; j < 10; j++) {
                float q = (y - muv[j]) / sg[j];
                float llv = -0.5f * q * q - __logf(sg[j]) - 0.91893853320467274f;
                tt[j] = lp[j] + llv; mm = fmaxf(mm, tt[j]);
            }
            float s2e = 0.f;
            #pragma unroll
            for (int j = 0; j < 10; j++) s2e += __expf(tt[j] - mm);
            float mdn = -(mm + __logf(s2e));
            #pragma unroll
            for (int j = 0; j < 10; j++) { bufA[t * 10 + j] = lp[j]; bufB[t * 10 + j] = sg[j]; bufC[t * 10 + j] = muv[j]; }
            mdnv[t] = mdn; mdnb[t] = b;
        }
        __syncthreads();
        {
            float4* oA = (float4*)&out_logpi[m0 * 10];
            float4* oB = (float4*)&out_sigma[m0 * 10];
            float4* oC = (float4*)&out_mu[m0 * 10];
            const float4* bA = (const float4*)bufA;
            const float4* bB = (const float4*)bufB;
            const float4* bC = (const float4*)bufC;
            #pragma unroll
            for (int i4 = t; i4 < 320; i4 += 256) { oA[i4] = bA[i4]; oB[i4] = bB[i4]; oC[i4] = bC[i4]; }
        }
        if (t < 64) {   // deterministic fixed-order partial sums: 8 chunks x 8 batches
            int bb = t & 7, chunk = t >> 3;
            float s = 0.f; int cnt = 0;
            for (int rr = chunk * 16; rr < chunk * 16 + 16; rr++)
                if (mdnb[rr] == bb) { s += mdnv[rr]; cnt++; }
            psLds[chunk][bb] = s; pcLds[chunk][bb] = (float)cnt;
        }
        __syncthreads();
        if (t < 8) {
            float s = 0.f, cnt = 0.f;
            #pragma unroll
            for (int chunk = 0; chunk < 8; chunk++) { s += psLds[chunk][t]; cnt += pcLds[chunk][t]; }
            mdn_psum[bid * 8 + t] = s; mdn_pcnt[bid * 8 + t] = cnt;
        }
    }
}

// ---------------- k7: prob = segment mean (1024 psum rows) ----------------
__global__ __launch_bounds__(256) void k7_prob(const float* __restrict__ psum, const float* __restrict__ pcnt,
        float* __restrict__ prob) {
    int b = blockIdx.x, t = threadIdx.x;
    float s = 0, c = 0;
    for (int idx = t; idx < 1024; idx += 256) { s += psum[idx * 8 + b]; c += pcnt[idx * 8 + b]; }
    __shared__ float rs[256], rc[256];
    rs[t] = s; rc[t] = c;
    __syncthreads();
    for (int off = 128; off > 0; off >>= 1) {
        if (t < off) { rs[t] += rs[t + off]; rc[t] += rc[t + off]; }
        __syncthreads();
    }
    if (t == 0) prob[b] = rs[0] / fmaxf(rc[0], 1.f);
}

extern "C" void kernel_launch(void* const* d_in, const int* in_sizes, int n_in,
                              void* d_out, int out_size, void* d_ws, size_t ws_size,
                              hipStream_t stream) {
    const float* flig  = (const float*)d_in[0];
    const float* posl  = (const float*)d_in[1];
    const float* frec  = (const float*)d_in[3];
    const float* posr  = (const float*)d_in[4];
    const int*   mask  = (const int*)d_in[6];
    const float* W1    = (const float*)d_in[7];
    const float* b1    = (const float*)d_in[8];
    const float* g1    = (const float*)d_in[9];
    const float* beta1 = (const float*)d_in[10];
    const float* Wpi   = (const float*)d_in[11];
    const float* bpi   = (const float*)d_in[12];
    const float* Wsig  = (const float*)d_in[13];
    const float* bsig  = (const float*)d_in[14];
    const float* Wmu   = (const float*)d_in[15];
    const float* bmu   = (const float*)d_in[16];
    const float* Wc1   = (const float*)d_in[17];
    const float* bc1   = (const float*)d_in[18];
    const float* gc    = (const float*)d_in[19];
    const float* betac = (const float*)d_in[20];
    const float* Wc2   = (const float*)d_in[21];
    const float* bc2   = (const float*)d_in[22];

    float* ws = (float*)d_ws;
    float* U      = ws;                 // 65536
    float* V      = ws + 65536;         // 524288 (end 589824)
    float* scale1 = ws + 589824;        // 128
    float* shift1 = ws + 589952;
    float* Af     = ws + 590080;
    float* Bf2    = ws + 590208;        // (end 590336)
    ushort* wB    = (ushort*)(ws + 590336);   // 16384 bf16 = 8192 f (end 598528)
    ushort* wBg   = (ushort*)(ws + 598528);   // 4096 bf16 = 2048 f (end 600576)
    float* bn2s   = ws + 600576;        // 256*128 = 32768 (end 633344)
    float* bn2s2  = ws + 633344;        // (end 666112)
    float* psum   = ws + 666112;        // 8192 (end 674304)
    float* pcnt   = ws + 674304;        // (end 682496)
    float* partS  = ws + 682496;        // 576*128 = 73728 (end 756224)
    float* partS2 = ws + 756224;        // (end 829952)

    float* out = (float*)d_out;
    float* out_logpi   = out;
    float* out_sigma   = out + 1310720;
    float* out_mu      = out + 2621440;
    float* out_prob    = out + 3932160;
    float* out_contact = out + 3932168;
    float* out_truth   = out + 4194312;

    k1_uv<<<dim3(704), dim3(128), 0, stream>>>(flig, frec, W1, b1, Wc1, Wpi, Wsig, Wmu,
        U, V, partS, partS2, wB, wBg);
    k2_bn1<<<dim3(1), dim3(1024), 0, stream>>>(partS, partS2, g1, beta1, scale1, shift1);
    k_stats<<<dim3(256), dim3(256), 0, stream>>>(U, V, scale1, shift1, wB, bc1, bn2s, bn2s2);
    k4_bn2<<<dim3(1), dim3(1024), 0, stream>>>(bn2s, bn2s2, gc, betac, bc1, Af, Bf2);
    k_mix<<<dim3(3072), dim3(256), 0, stream>>>(mask, U, V, scale1, shift1, wB, wBg,
        Af, Bf2, Wc2, bc2, bpi, bsig, bmu, posl, posr,
        out_contact, out_truth, out_logpi, out_sigma, out_mu, psum, pcnt);
    k7_prob<<<dim3(8), dim3(256), 0, stream>>>(psum, pcnt, out_prob);
}